// Round 19
// baseline (163.765 us; speedup 1.0000x reference)
//
#include <hip/hip_runtime.h>
#include <hip/hip_bf16.h>
#include <stdint.h>

typedef __attribute__((ext_vector_type(8)))  __bf16 bf16x8;
typedef __attribute__((ext_vector_type(4)))  float  f32x4;
typedef __attribute__((ext_vector_type(16))) float  f32x16;
typedef __hip_bfloat16 bf16_t;

#define T_SEQ 2048
#define D_MODEL 1024
#define N_HEADS 16
#define N_KV 4
#define HD 64
#define LDQKV 1536
#define KDIM 1024

// Convert 16 consecutive fp32 (4x float4) -> 16 bf16 (2x int4)
__device__ inline void cvt16(const float4* __restrict__ g, int4* __restrict__ s) {
  float4 v0 = g[0], v1 = g[1], v2 = g[2], v3 = g[3];
  union { int4 i[2]; __hip_bfloat162 h[8]; } u;
  u.h[0] = __float22bfloat162_rn(make_float2(v0.x, v0.y));
  u.h[1] = __float22bfloat162_rn(make_float2(v0.z, v0.w));
  u.h[2] = __float22bfloat162_rn(make_float2(v1.x, v1.y));
  u.h[3] = __float22bfloat162_rn(make_float2(v1.z, v1.w));
  u.h[4] = __float22bfloat162_rn(make_float2(v2.x, v2.y));
  u.h[5] = __float22bfloat162_rn(make_float2(v2.z, v2.w));
  u.h[6] = __float22bfloat162_rn(make_float2(v3.x, v3.y));
  u.h[7] = __float22bfloat162_rn(make_float2(v3.z, v3.w));
  s[0] = u.i[0]; s[1] = u.i[1];
}

__device__ inline void storeC(bf16_t* p, float v) { *p = __float2bfloat16(v); }
__device__ inline void storeC(float* p, float v) { *p = v; }

// v_permlane32_swap_b32 vdst, vsrc: after plswap(a,b): a={a_L,b_L}, b={a_U,b_U}
__device__ inline void plswap(unsigned& a, unsigned& b) {
  asm volatile("v_permlane32_swap_b32 %0, %1" : "+v"(a), "+v"(b));
}

// HW transcendental exp2 (input already in log2 domain)
__device__ inline float fexp2(float x) {
  float r; asm("v_exp_f32 %0, %1" : "=v"(r) : "v"(x)); return r;
}
// HW packed fp32->bf16 (T12 recipe; no builtin on gfx950)
__device__ inline unsigned cvtpk(float lo, float hi) {
  unsigned r; asm("v_cvt_pk_bf16_f32 %0, %1, %2" : "=v"(r) : "v"(lo), "v"(hi));
  return r;
}

// async global->LDS, 16B per lane; lds dest must be wave-uniform base.
__device__ inline void gll16(const bf16_t* g, bf16_t* l) {
  __builtin_amdgcn_global_load_lds(
      (const __attribute__((address_space(1))) void*)g,
      (__attribute__((address_space(3))) void*)l, 16, 0, 0);
}

// ---------------------------------------------------------------------------
// fp32 -> bf16 bulk convert, x + all weights in ONE launch (units of 16 elem)
// ---------------------------------------------------------------------------
__global__ __launch_bounds__(256) void all_cvt(
    const float* __restrict__ x,
    const float* __restrict__ Wq, const float* __restrict__ Wk,
    const float* __restrict__ Wv, const float* __restrict__ Wo,
    bf16_t* __restrict__ xb, bf16_t* __restrict__ wqkvb,
    bf16_t* __restrict__ wob) {
  const int i = blockIdx.x * 256 + threadIdx.x;
  const float* s; bf16_t* d; int off;
  if (i < 524288)      { s = x;  d = xb;                   off = i; }
  else if (i < 589824) { s = Wq; d = wqkvb;                off = i - 524288; }
  else if (i < 606208) { s = Wk; d = wqkvb + 1024 * 1024;  off = i - 589824; }
  else if (i < 622592) { s = Wv; d = wqkvb + 1280 * 1024;  off = i - 606208; }
  else                 { s = Wo; d = wob;                  off = i - 622592; }
  cvt16((const float4*)s + off * 4, (int4*)d + off * 2);
}

// ---------------------------------------------------------------------------
// GEMM bf16 x bf16 (unchanged — passing, fused QKV epilogue)
// ---------------------------------------------------------------------------
template <int MODE, typename CT>
__global__ __launch_bounds__(256) void gemm_bb(
    const bf16_t* __restrict__ A, const bf16_t* __restrict__ W,
    CT* __restrict__ C, const int ldC,
    const float* __restrict__ cosb, const float* __restrict__ sinb,
    const float* __restrict__ qs, const float* __restrict__ ks,
    bf16_t* __restrict__ v_t)
{
  __shared__ bf16_t As[128 * 32];
  __shared__ bf16_t Bs[128 * 32];
  const int tid = threadIdx.x;
  const int lane = tid & 63;
  const int wv = tid >> 6;
  const int wr = wv >> 1, wc = wv & 1;
  const int m0 = blockIdx.y * 128;
  const int n0 = blockIdx.x * 128;

  const int srow = lane >> 2;
  const int scol = (lane & 3) * 8;
  const bf16_t* gA = A + (size_t)(m0 + 32 * wv + srow) * KDIM + scol;
  const bf16_t* gB = W + (size_t)(n0 + 32 * wv + srow) * KDIM + scol;
  bf16_t* lA = As + wv * 1024;
  bf16_t* lB = Bs + wv * 1024;

  f32x4 acc[4][4];
#pragma unroll
  for (int m = 0; m < 4; ++m)
#pragma unroll
    for (int n = 0; n < 4; ++n)
      acc[m][n] = {0.f, 0.f, 0.f, 0.f};

  const int fr = lane & 15;
  const int fq = lane >> 4;

  for (int k0 = 0; k0 < KDIM; k0 += 32) {
    gll16(gA + k0, lA);
    gll16(gA + 16 * KDIM + k0, lA + 512);
    gll16(gB + k0, lB);
    gll16(gB + 16 * KDIM + k0, lB + 512);
    __syncthreads();
    bf16x8 af[4], bfv[4];
#pragma unroll
    for (int m = 0; m < 4; ++m)
      af[m] = *(const bf16x8*)(&As[(wr * 64 + m * 16 + fr) * 32 + fq * 8]);
#pragma unroll
    for (int n = 0; n < 4; ++n)
      bfv[n] = *(const bf16x8*)(&Bs[(wc * 64 + n * 16 + fr) * 32 + fq * 8]);
#pragma unroll
    for (int m = 0; m < 4; ++m)
#pragma unroll
      for (int n = 0; n < 4; ++n)
        acc[m][n] = __builtin_amdgcn_mfma_f32_16x16x32_bf16(af[m], bfv[n],
                                                            acc[m][n], 0, 0, 0);
    __syncthreads();
  }

  if (MODE == 0 || n0 < 1280) {
    if (MODE == 1) {
      const float* stab = (n0 < 1024) ? qs : ks;
      float sc0 = stab[fr], sc1 = stab[16 + fr], sc2 = stab[32 + fr], sc3 = stab[48 + fr];
#pragma unroll
      for (int m = 0; m < 4; ++m)
#pragma unroll
        for (int r = 0; r < 4; ++r) {
          const int row = m0 + wr * 64 + m * 16 + fq * 4 + r;
          const int t = row & (T_SEQ - 1);
          float ss = acc[m][0][r] * acc[m][0][r] + acc[m][1][r] * acc[m][1][r]
                   + acc[m][2][r] * acc[m][2][r] + acc[m][3][r] * acc[m][3][r];
          ss += __shfl_xor(ss, 1);
          ss += __shfl_xor(ss, 2);
          ss += __shfl_xor(ss, 4);
          ss += __shfl_xor(ss, 8);
          const float nrm = rsqrtf(ss * (1.f / 64.f) + 1e-6f);
          const float v0 = acc[m][0][r] * nrm * sc0;
          const float v1 = acc[m][1][r] * nrm * sc1;
          const float v2 = acc[m][2][r] * nrm * sc2;
          const float v3 = acc[m][3][r] * nrm * sc3;
          const float c = cosb[t * 16 + fr];
          const float s = sinb[t * 16 + fr];
          const float r0 = v0 * c - v1 * s;
          const float r1 = v0 * s + v1 * c;
          bf16_t* p = (bf16_t*)C + (size_t)row * ldC + n0 + wc * 64 + fr;
          p[0]  = __float2bfloat16(r0);
          p[16] = __float2bfloat16(r1);
          p[32] = __float2bfloat16(v2);
          p[48] = __float2bfloat16(v3);
        }
    } else {
#pragma unroll
      for (int m = 0; m < 4; ++m)
#pragma unroll
        for (int n = 0; n < 4; ++n)
#pragma unroll
          for (int r = 0; r < 4; ++r) {
            const int row = wr * 64 + m * 16 + fq * 4 + r;
            const int col = wc * 64 + n * 16 + fr;
            storeC(&C[(size_t)(m0 + row) * ldC + n0 + col], acc[m][n][r]);
          }
    }
  } else {
#pragma unroll
    for (int m = 0; m < 4; ++m) {
      const int row0 = m0 + wr * 64 + m * 16 + fq * 4;
      const int b = row0 >> 11, t0 = row0 & (T_SEQ - 1);
#pragma unroll
      for (int n = 0; n < 4; ++n) {
        const int vcol = n0 - 1280 + wc * 64 + n * 16 + fr;
        const int g = b * 4 + (vcol >> 6);
        const int d = vcol & 63;
        uint2 pk2;
        pk2.x = cvtpk(acc[m][n][0], acc[m][n][1]);
        pk2.y = cvtpk(acc[m][n][2], acc[m][n][3]);
        *(uint2*)(v_t + ((size_t)g * HD + d) * T_SEQ + t0) = pk2;
      }
    }
  }
}

// ---------------------------------------------------------------------------
// Causal GQA flash attention v15 — v14 (8-wave split-k, KVBLK=128) with:
//  * global_load_lds staging, swizzle moved to per-lane GLOBAL address
//    (K col ^= lane>>3, V col ^= (lane>>3)&3 — lane-only constants; LDS
//    dest linear). Waves 0-3 stage K subtiles, 4-7 stage V subtiles.
//  * combined per-round softmax: QK(t0),QK(t1) -> ONE max/defer/rescale over
//    both subtiles -> PV(t0),PV(t1). Halves the serial SM section per round.
// Merge/epilogue identical to v13/v14 (passing).
// ---------------------------------------------------------------------------
__global__ __launch_bounds__(512) void attn(
    const bf16_t* __restrict__ qkv, const bf16_t* __restrict__ v_t,
    bf16_t* __restrict__ y)
{
  __shared__ int4 lds[4096];      // 64 KB: dbuf x (K 16KB + V 16KB)
  const int tid  = threadIdx.x;   // 0..511
  const int lane = tid & 63;
  const int w    = tid >> 6;      // 0..7
  const int spair= w >> 1;        // 0..3: strip within block
  const int h    = w & 1;         // split-k parity (subtile pair {2h,2h+1})
  const int ql   = lane & 31;
  const int hi   = lane >> 5;
  const int id   = (int)blockIdx.x;          // 0..511
  const int low3 = id & 7;
  const int rest = id >> 3;                  // 0..63
  const int gsel = rest & 1;
  const int hh   = (rest >> 1) & 3;
  const int p    = rest >> 3;                // 0..7
  const int g16  = low3 + 8 * gsel;          // b*4+kvh (same-XCD clustering)
  const int b    = g16 >> 2, kvh = g16 & 3;
  const int hd   = kvh * 4 + hh;
  const int sA   = 4 * p + spair;            // pass-0 strip; pass-1 = 63-sA
  const float SCALE_LOG2 = 0.125f * 1.44269504089f;

  // --- gll16 staging setup: wave w<4 stages K subtile w; w>=4 V subtile w-4.
  // Inverse-swizzled global source, linear LDS dest (slot = w*256 + j*64 + lane).
  const bool isK = (w < 4);
  const int su  = isK ? w : (w - 4);
  const bf16_t* gsrc0;   // call-j source = gsrc0 + j*strideJ; round += strideR
  size_t strideJ, strideR;
  if (isK) {
    const int row = su * 32 + (lane >> 3);
    const int col = ((lane & 7) ^ (lane >> 3)) * 8;
    gsrc0 = qkv + (size_t)(b * T_SEQ + row) * LDQKV + 1024 + kvh * HD + col;
    strideJ = (size_t)8 * LDQKV;
    strideR = (size_t)128 * LDQKV;
  } else {
    const int row = lane >> 2;
    const int col = ((lane & 3) ^ ((lane >> 3) & 3)) * 8 + su * 32;
    gsrc0 = v_t + (size_t)((b * N_KV + kvh) * HD + row) * T_SEQ + col;
    strideJ = (size_t)16 * T_SEQ;
    strideR = 128;
  }
  const int ldsSlotBase = w * 256;   // int4 slot (K: w*256; V: 1024+(w-4)*256)
  const int ldsOff = isK ? ldsSlotBase : (1024 + su * 256);

  // fragment read indices (subtile-relative)
  int kridx[4];
#pragma unroll
  for (int c = 0; c < 4; ++c)
    kridx[c] = ql * 8 + ((2 * c + hi) ^ (ql & 7));
  const int vsw = (ql >> 1) & 3;
  const int v0r = ql * 4 + (hi ^ vsw);
  const int v1r = ql * 4 + ((2 + hi) ^ vsw);
  const int v2r = (ql + 32) * 4 + (hi ^ vsw);
  const int v3r = (ql + 32) * 4 + ((2 + hi) ^ vsw);

  union ob { unsigned uu[4]; bf16x8 v; } onesf;
#pragma unroll
  for (int i = 0; i < 4; ++i) onesf.uu[i] = 0x3F803F80u;

  f32x16 zro;
#pragma unroll
  for (int i = 0; i < 16; ++i) zro[i] = 0.f;

  float* lf = (float*)lds;
  int buf = 0;
#pragma unroll
  for (int pi = 0; pi < 2; ++pi) {
    const int s = pi ? (63 - sA) : sA;
    const int q_glob = s * 32 + ql;
    const int nt = s + 1;                       // strip's 32-k tiles
    const int nR = pi ? (16 - p) : (p + 1);     // block-uniform 128-k rounds

    // Q fragments, pre-scaled into log2 domain
    const bf16_t* Qrow = qkv + (size_t)(b * T_SEQ + q_glob) * LDQKV + hd * HD + hi * 8;
    bf16x8 qfrag[4];
#pragma unroll
    for (int c = 0; c < 4; ++c) {
      bf16x8 raw = *(const bf16x8*)(Qrow + c * 16);
      bf16x8 sc;
#pragma unroll
      for (int j = 0; j < 8; ++j)
        sc[j] = (__bf16)((float)raw[j] * SCALE_LOG2);
      qfrag[c] = sc;
    }

    f32x16 acc0, acc1, accL;
#pragma unroll
    for (int i = 0; i < 16; ++i) { acc0[i] = 0.f; acc1[i] = 0.f; accL[i] = 0.f; }
    float m_run = -1e30f;

    // prologue: stage round-0 into current buf via global_load_lds
    const bf16_t* gsrc = gsrc0;
    {
      bf16_t* lb = (bf16_t*)&lds[buf * 2048 + ldsOff];
#pragma unroll
      for (int j = 0; j < 4; ++j)
        gll16(gsrc + j * strideJ, lb + j * 512);
    }
    gsrc += strideR;
    __syncthreads();

    for (int r = 0; r < nR; ++r) {
      const bool more = (r + 1 < nR);
      if (more) {
        bf16_t* lb = (bf16_t*)&lds[(buf ^ 1) * 2048 + ldsOff];
#pragma unroll
        for (int j = 0; j < 4; ++j)
          gll16(gsrc + j * strideJ, lb + j * 512);
        gsrc += strideR;
      }

      const int t0 = 4 * r + 2 * h;
      const int t1 = t0 + 1;
      if (t0 < nt) {
        const bool act1 = (t1 < nt);
        const int kb0 = buf * 2048 + (2 * h) * 256;
        const int kb1 = kb0 + 256;
        const int vb0 = buf * 2048 + 1024 + (2 * h) * 256;
        const int vb1 = vb0 + 256;

        bf16x8 ka0 = *(const bf16x8*)&lds[kb0 + kridx[0]];
        bf16x8 ka1 = *(const bf16x8*)&lds[kb0 + kridx[1]];
        bf16x8 ka2 = *(const bf16x8*)&lds[kb0 + kridx[2]];
        bf16x8 ka3 = *(const bf16x8*)&lds[kb0 + kridx[3]];
        bf16x8 kb0f = *(const bf16x8*)&lds[kb1 + kridx[0]];
        bf16x8 kb1f = *(const bf16x8*)&lds[kb1 + kridx[1]];
        bf16x8 kb2f = *(const bf16x8*)&lds[kb1 + kridx[2]];
        bf16x8 kb3f = *(const bf16x8*)&lds[kb1 + kridx[3]];

        __builtin_amdgcn_s_setprio(1);
        f32x16 st0 = __builtin_amdgcn_mfma_f32_32x32x16_bf16(ka0, qfrag[0], zro, 0, 0, 0);
        st0 = __builtin_amdgcn_mfma_f32_32x32x16_bf16(ka1, qfrag[1], st0, 0, 0, 0);
        st0 = __builtin_amdgcn_mfma_f32_32x32x16_bf16(ka2, qfrag[2], st0, 0, 0, 0);
        st0 = __builtin_amdgcn_mfma_f32_32x32x16_bf16(ka3, qfrag[3], st0, 0, 0, 0);
        f32x16 st1 = __builtin_amdgcn_mfma_f32_32x32x16_bf16(kb0f, qfrag[0], zro, 0, 0, 0);
        st1 = __builtin_amdgcn_mfma_f32_32x32x16_bf16(kb1f, qfrag[1], st1, 0, 0, 0);
        st1 = __builtin_amdgcn_mfma_f32_32x32x16_bf16(kb2f, qfrag[2], st1, 0, 0, 0);
        st1 = __builtin_amdgcn_mfma_f32_32x32x16_bf16(kb3f, qfrag[3], st1, 0, 0, 0);
        __builtin_amdgcn_s_setprio(0);

        // masking: diagonal tile per-register; inactive t1 wholesale
        if (t0 == nt - 1) {
#pragma unroll
          for (int rr = 0; rr < 16; ++rr) {
            const int kg = (t0 << 5) + (rr & 3) + 8 * (rr >> 2) + 4 * hi;
            if (kg > q_glob) st0[rr] = -1e30f;
          }
        }
        if (!act1) {
#pragma unroll
          for (int rr = 0; rr < 16; ++rr) st1[rr] = -1e30f;
        } else if (t1 == nt - 1) {
#pragma unroll
          for (int rr = 0; rr < 16; ++rr) {
            const int kg = (t1 << 5) + (rr & 3) + 8 * (rr >> 2) + 4 * hi;
            if (kg > q_glob) st1[rr] = -1e30f;
          }
        }

        // combined max over both subtiles (one defer/rescale per round)
        float ma = fmaxf(fmaxf(fmaxf(st0[0], st0[1]), fmaxf(st0[2], st0[3])),
                         fmaxf(fmaxf(st0[4], st0[5]), fmaxf(st0[6], st0[7])));
        ma = fmaxf(ma,
             fmaxf(fmaxf(fmaxf(st0[8], st0[9]), fmaxf(st0[10], st0[11])),
                   fmaxf(fmaxf(st0[12], st0[13]), fmaxf(st0[14], st0[15]))));
        float mb = fmaxf(fmaxf(fmaxf(st1[0], st1[1]), fmaxf(st1[2], st1[3])),
                         fmaxf(fmaxf(st1[4], st1[5]), fmaxf(st1[6], st1[7])));
        mb = fmaxf(mb,
             fmaxf(fmaxf(fmaxf(st1[8], st1[9]), fmaxf(st1[10], st1[11])),
                   fmaxf(fmaxf(st1[12], st1[13]), fmaxf(st1[14], st1[15]))));
        const float bmax = fmaxf(ma, mb);
        if (__any(bmax > m_run + 8.f)) {        // T13 defer-max
          const float rmax = fmaxf(bmax, __shfl_xor(bmax, 32));
          const float mnew = fmaxf(m_run, rmax);
          const float corr = fexp2(m_run - mnew);
#pragma unroll
          for (int i = 0; i < 16; ++i) { acc0[i] *= corr; acc1[i] *= corr; }
          accL[0] *= corr;
          m_run = mnew;
        }
        float p0[16], p1[16];
#pragma unroll
        for (int rr = 0; rr < 16; ++rr) p0[rr] = fexp2(st0[rr] - m_run);
#pragma unroll
        for (int rr = 0; rr < 16; ++rr) p1[rr] = fexp2(st1[rr] - m_run);

        unsigned wa[8], wb[8];
#pragma unroll
        for (int i = 0; i < 8; ++i) wa[i] = cvtpk(p0[2 * i], p0[2 * i + 1]);
        plswap(wa[0], wa[2]); plswap(wa[1], wa[3]);
        plswap(wa[4], wa[6]); plswap(wa[5], wa[7]);
#pragma unroll
        for (int i = 0; i < 8; ++i) wb[i] = cvtpk(p1[2 * i], p1[2 * i + 1]);
        plswap(wb[0], wb[2]); plswap(wb[1], wb[3]);
        plswap(wb[4], wb[6]); plswap(wb[5], wb[7]);
        union fu { unsigned uu2[4]; bf16x8 v; };
        fu fa1, fa2, fb1, fb2;
        fa1.uu2[0] = wa[0]; fa1.uu2[1] = wa[1]; fa1.uu2[2] = wa[2]; fa1.uu2[3] = wa[3];
        fa2.uu2[0] = wa[4]; fa2.uu2[1] = wa[5]; fa2.uu2[2] = wa[6]; fa2.uu2[3] = wa[7];
        fb1.uu2[0] = wb[0]; fb1.uu2[1] = wb[1]; fb1.uu2[2] = wb[2]; fb1.uu2[3] = wb[3];
        fb2.uu2[0] = wb[4]; fb2.uu2[1] = wb[5]; fb2.uu2[2] = wb[6]; fb2.uu2[3] = wb[7];

        bf16x8 va0 = *(const bf16x8*)&lds[vb0 + v0r];
        bf16x8 va1 = *(const bf16x8*)&lds[vb0 + v1r];
        bf16x8 va2 = *(const bf16x8*)&lds[vb0 + v2r];
        bf16x8 va3 = *(const bf16x8*)&lds[vb0 + v3r];
        bf16x8 vb0f = *(const bf16x8*)&lds[vb1 + v0r];
        bf16x8 vb1f = *(const bf16x8*)&lds[vb1 + v1r];
        bf16x8 vb2f = *(const bf16x8*)&lds[vb1 + v2r];
        bf16x8 vb3f = *(const bf16x8*)&lds[vb1 + v3r];

        __builtin_amdgcn_s_setprio(1);
        acc0 = __builtin_amdgcn_mfma_f32_32x32x16_bf16(va0, fa1.v, acc0, 0, 0, 0);
        acc0 = __builtin_amdgcn_mfma_f32_32x32x16_bf16(va1, fa2.v, acc0, 0, 0, 0);
        acc1 = __builtin_amdgcn_mfma_f32_32x32x16_bf16(va2, fa1.v, acc1, 0, 0, 0);
        acc1 = __builtin_amdgcn_mfma_f32_32x32x16_bf16(va3, fa2.v, acc1, 0, 0, 0);
        acc0 = __builtin_amdgcn_mfma_f32_32x32x16_bf16(vb0f, fb1.v, acc0, 0, 0, 0);
        acc0 = __builtin_amdgcn_mfma_f32_32x32x16_bf16(vb1f, fb2.v, acc0, 0, 0, 0);
        acc1 = __builtin_amdgcn_mfma_f32_32x32x16_bf16(vb2f, fb1.v, acc1, 0, 0, 0);
        acc1 = __builtin_amdgcn_mfma_f32_32x32x16_bf16(vb3f, fb2.v, acc1, 0, 0, 0);
        accL = __builtin_amdgcn_mfma_f32_32x32x16_bf16(onesf.v, fa1.v, accL, 0, 0, 0);
        accL = __builtin_amdgcn_mfma_f32_32x32x16_bf16(onesf.v, fa2.v, accL, 0, 0, 0);
        accL = __builtin_amdgcn_mfma_f32_32x32x16_bf16(onesf.v, fb1.v, accL, 0, 0, 0);
        accL = __builtin_amdgcn_mfma_f32_32x32x16_bf16(onesf.v, fb2.v, accL, 0, 0, 0);
        __builtin_amdgcn_s_setprio(0);
      }

      __syncthreads();
      buf ^= 1;
    }

    // ---- split-k merge: h=1 publishes partials, h=0 merges & stores ----
    float cA = 1.f, cB = 0.f, l_mrg = 0.f;
    if (h == 1) {
      const int fb = spair * 1216 + lane * 19;
#pragma unroll
      for (int i = 0; i < 16; ++i) lf[fb + i] = acc0[i];
      lf[fb + 16] = m_run;
      lf[fb + 17] = accL[0];
    }
    __syncthreads();
    if (h == 0) {
      const int fb = spair * 1216 + lane * 19;
      const float mB = lf[fb + 16], lB = lf[fb + 17];
      const float mM = fmaxf(m_run, mB);
      cA = fexp2(m_run - mM);
      cB = fexp2(mB - mM);
      l_mrg = accL[0] * cA + lB * cB;
#pragma unroll
      for (int i = 0; i < 16; ++i) acc0[i] = acc0[i] * cA + lf[fb + i] * cB;
    }
    __syncthreads();
    if (h == 1) {
      const int fb2 = spair * 1088 + lane * 17;
#pragma unroll
      for (int i = 0; i < 16; ++i) lf[fb2 + i] = acc1[i];
    }
    __syncthreads();
    if (h == 0) {
      const int fb2 = spair * 1088 + lane * 17;
#pragma unroll
      for (int i = 0; i < 16; ++i) acc1[i] = acc1[i] * cA + lf[fb2 + i] * cB;
      const float inv = 1.f / l_mrg;
      bf16_t* yrow = y + (size_t)(b * T_SEQ + q_glob) * D_MODEL + hd * HD;
#pragma unroll
      for (int gg = 0; gg < 4; ++gg) {
        uint2 o0, o1;
        o0.x = cvtpk(acc0[4 * gg + 0] * inv, acc0[4 * gg + 1] * inv);
        o0.y = cvtpk(acc0[4 * gg + 2] * inv, acc0[4 * gg + 3] * inv);
        o1.x = cvtpk(acc1[4 * gg + 0] * inv, acc1[4 * gg + 1] * inv);
        o1.y = cvtpk(acc1[4 * gg + 2] * inv, acc1[4 * gg + 3] * inv);
        *(uint2*)(yrow + 8 * gg + 4 * hi)      = o0;
        *(uint2*)(yrow + 32 + 8 * gg + 4 * hi) = o1;
      }
    }
    __syncthreads();   // fence LDS reads before next pass's prologue writes
  }
}

// ---------------------------------------------------------------------------
extern "C" void kernel_launch(void* const* d_in, const int* in_sizes, int n_in,
                              void* d_out, int out_size, void* d_ws,
                              size_t ws_size, hipStream_t stream) {
  const float* x    = (const float*)d_in[0];
  const float* cosb = (const float*)d_in[1];
  const float* sinb = (const float*)d_in[2];
  const float* Wq   = (const float*)d_in[3];
  const float* Wk   = (const float*)d_in[4];
  const float* Wv   = (const float*)d_in[5];
  const float* Wo   = (const float*)d_in[6];
  const float* qs   = (const float*)d_in[7];
  const float* ks   = (const float*)d_in[8];
  float* out = (float*)d_out;   // reference output dtype is float32

  char* ws = (char*)d_ws;
  bf16_t* qkv   = (bf16_t*)ws;                       // 25165824 B
  bf16_t* v_t   = (bf16_t*)(ws + 25165824);          // 4194304 B
  bf16_t* y     = (bf16_t*)(ws + 29360128);          // 16777216 B (= xb alias)
  bf16_t* xb    = y;                                 // xb dead before attn writes y
  bf16_t* wqkvb = (bf16_t*)(ws + 46137344);          // 3145728 B
  bf16_t* wob   = (bf16_t*)(ws + 49283072);          // 2097152 B

  // 0. fp32 -> bf16 converts (one launch: x + all weights)
  all_cvt<<<dim3(2688), 256, 0, stream>>>(x, Wq, Wk, Wv, Wo, xb, wqkvb, wob);

  // 1. fused QKV projection + RMSNorm + RoPE + V-transpose
  gemm_bb<1, bf16_t><<<dim3(12, 64), 256, 0, stream>>>(
      xb, wqkvb, qkv, LDQKV, cosb, sinb, qs, ks, v_t);
  // 2. causal GQA flash attention -> y (8-wave split-k, KVBLK=128, gll16)
  attn<<<dim3(512), 512, 0, stream>>>(qkv, v_t, y);
  // 3. output projection
  gemm_bb<0, float><<<dim3(8, 64), 256, 0, stream>>>(
      y, wob, out, D_MODEL, nullptr, nullptr, nullptr, nullptr, nullptr);
}

// Round 20
// 160.355 us; speedup vs baseline: 1.0213x; 1.0213x over previous
//
#include <hip/hip_runtime.h>
#include <hip/hip_bf16.h>
#include <stdint.h>

typedef __attribute__((ext_vector_type(8)))  __bf16 bf16x8;
typedef __attribute__((ext_vector_type(4)))  float  f32x4;
typedef __attribute__((ext_vector_type(16))) float  f32x16;
typedef __hip_bfloat16 bf16_t;

#define T_SEQ 2048
#define D_MODEL 1024
#define N_HEADS 16
#define N_KV 4
#define HD 64
#define LDQKV 1536
#define KDIM 1024

// Convert 16 consecutive fp32 (4x float4) -> 16 bf16 (2x int4)
__device__ inline void cvt16(const float4* __restrict__ g, int4* __restrict__ s) {
  float4 v0 = g[0], v1 = g[1], v2 = g[2], v3 = g[3];
  union { int4 i[2]; __hip_bfloat162 h[8]; } u;
  u.h[0] = __float22bfloat162_rn(make_float2(v0.x, v0.y));
  u.h[1] = __float22bfloat162_rn(make_float2(v0.z, v0.w));
  u.h[2] = __float22bfloat162_rn(make_float2(v1.x, v1.y));
  u.h[3] = __float22bfloat162_rn(make_float2(v1.z, v1.w));
  u.h[4] = __float22bfloat162_rn(make_float2(v2.x, v2.y));
  u.h[5] = __float22bfloat162_rn(make_float2(v2.z, v2.w));
  u.h[6] = __float22bfloat162_rn(make_float2(v3.x, v3.y));
  u.h[7] = __float22bfloat162_rn(make_float2(v3.z, v3.w));
  s[0] = u.i[0]; s[1] = u.i[1];
}

__device__ inline void storeC(bf16_t* p, float v) { *p = __float2bfloat16(v); }
__device__ inline void storeC(float* p, float v) { *p = v; }

// v_permlane32_swap_b32 vdst, vsrc: after plswap(a,b): a={a_L,b_L}, b={a_U,b_U}
__device__ inline void plswap(unsigned& a, unsigned& b) {
  asm volatile("v_permlane32_swap_b32 %0, %1" : "+v"(a), "+v"(b));
}

// HW transcendental exp2 (input already in log2 domain)
__device__ inline float fexp2(float x) {
  float r; asm("v_exp_f32 %0, %1" : "=v"(r) : "v"(x)); return r;
}
// HW packed fp32->bf16 (T12 recipe; no builtin on gfx950)
__device__ inline unsigned cvtpk(float lo, float hi) {
  unsigned r; asm("v_cvt_pk_bf16_f32 %0, %1, %2" : "=v"(r) : "v"(lo), "v"(hi));
  return r;
}

// async global->LDS, 16B per lane; lds dest must be wave-uniform base.
__device__ inline void gll16(const bf16_t* g, bf16_t* l) {
  __builtin_amdgcn_global_load_lds(
      (const __attribute__((address_space(1))) void*)g,
      (__attribute__((address_space(3))) void*)l, 16, 0, 0);
}

// ---------------------------------------------------------------------------
// fp32 -> bf16 bulk convert, x + all weights in ONE launch (units of 16 elem)
// ---------------------------------------------------------------------------
__global__ __launch_bounds__(256) void all_cvt(
    const float* __restrict__ x,
    const float* __restrict__ Wq, const float* __restrict__ Wk,
    const float* __restrict__ Wv, const float* __restrict__ Wo,
    bf16_t* __restrict__ xb, bf16_t* __restrict__ wqkvb,
    bf16_t* __restrict__ wob) {
  const int i = blockIdx.x * 256 + threadIdx.x;
  const float* s; bf16_t* d; int off;
  if (i < 524288)      { s = x;  d = xb;                   off = i; }
  else if (i < 589824) { s = Wq; d = wqkvb;                off = i - 524288; }
  else if (i < 606208) { s = Wk; d = wqkvb + 1024 * 1024;  off = i - 589824; }
  else if (i < 622592) { s = Wv; d = wqkvb + 1280 * 1024;  off = i - 606208; }
  else                 { s = Wo; d = wob;                  off = i - 622592; }
  cvt16((const float4*)s + off * 4, (int4*)d + off * 2);
}

// ---------------------------------------------------------------------------
// GEMM bf16 x bf16 (passing, fused QKV epilogue)
// ---------------------------------------------------------------------------
template <int MODE, typename CT>
__global__ __launch_bounds__(256) void gemm_bb(
    const bf16_t* __restrict__ A, const bf16_t* __restrict__ W,
    CT* __restrict__ C, const int ldC,
    const float* __restrict__ cosb, const float* __restrict__ sinb,
    const float* __restrict__ qs, const float* __restrict__ ks,
    bf16_t* __restrict__ v_t)
{
  __shared__ bf16_t As[128 * 32];
  __shared__ bf16_t Bs[128 * 32];
  const int tid = threadIdx.x;
  const int lane = tid & 63;
  const int wv = tid >> 6;
  const int wr = wv >> 1, wc = wv & 1;
  const int m0 = blockIdx.y * 128;
  const int n0 = blockIdx.x * 128;

  const int srow = lane >> 2;
  const int scol = (lane & 3) * 8;
  const bf16_t* gA = A + (size_t)(m0 + 32 * wv + srow) * KDIM + scol;
  const bf16_t* gB = W + (size_t)(n0 + 32 * wv + srow) * KDIM + scol;
  bf16_t* lA = As + wv * 1024;
  bf16_t* lB = Bs + wv * 1024;

  f32x4 acc[4][4];
#pragma unroll
  for (int m = 0; m < 4; ++m)
#pragma unroll
    for (int n = 0; n < 4; ++n)
      acc[m][n] = {0.f, 0.f, 0.f, 0.f};

  const int fr = lane & 15;
  const int fq = lane >> 4;

  for (int k0 = 0; k0 < KDIM; k0 += 32) {
    gll16(gA + k0, lA);
    gll16(gA + 16 * KDIM + k0, lA + 512);
    gll16(gB + k0, lB);
    gll16(gB + 16 * KDIM + k0, lB + 512);
    __syncthreads();
    bf16x8 af[4], bfv[4];
#pragma unroll
    for (int m = 0; m < 4; ++m)
      af[m] = *(const bf16x8*)(&As[(wr * 64 + m * 16 + fr) * 32 + fq * 8]);
#pragma unroll
    for (int n = 0; n < 4; ++n)
      bfv[n] = *(const bf16x8*)(&Bs[(wc * 64 + n * 16 + fr) * 32 + fq * 8]);
#pragma unroll
    for (int m = 0; m < 4; ++m)
#pragma unroll
      for (int n = 0; n < 4; ++n)
        acc[m][n] = __builtin_amdgcn_mfma_f32_16x16x32_bf16(af[m], bfv[n],
                                                            acc[m][n], 0, 0, 0);
    __syncthreads();
  }

  if (MODE == 0 || n0 < 1280) {
    if (MODE == 1) {
      const float* stab = (n0 < 1024) ? qs : ks;
      float sc0 = stab[fr], sc1 = stab[16 + fr], sc2 = stab[32 + fr], sc3 = stab[48 + fr];
#pragma unroll
      for (int m = 0; m < 4; ++m)
#pragma unroll
        for (int r = 0; r < 4; ++r) {
          const int row = m0 + wr * 64 + m * 16 + fq * 4 + r;
          const int t = row & (T_SEQ - 1);
          float ss = acc[m][0][r] * acc[m][0][r] + acc[m][1][r] * acc[m][1][r]
                   + acc[m][2][r] * acc[m][2][r] + acc[m][3][r] * acc[m][3][r];
          ss += __shfl_xor(ss, 1);
          ss += __shfl_xor(ss, 2);
          ss += __shfl_xor(ss, 4);
          ss += __shfl_xor(ss, 8);
          const float nrm = rsqrtf(ss * (1.f / 64.f) + 1e-6f);
          const float v0 = acc[m][0][r] * nrm * sc0;
          const float v1 = acc[m][1][r] * nrm * sc1;
          const float v2 = acc[m][2][r] * nrm * sc2;
          const float v3 = acc[m][3][r] * nrm * sc3;
          const float c = cosb[t * 16 + fr];
          const float s = sinb[t * 16 + fr];
          const float r0 = v0 * c - v1 * s;
          const float r1 = v0 * s + v1 * c;
          bf16_t* p = (bf16_t*)C + (size_t)row * ldC + n0 + wc * 64 + fr;
          p[0]  = __float2bfloat16(r0);
          p[16] = __float2bfloat16(r1);
          p[32] = __float2bfloat16(v2);
          p[48] = __float2bfloat16(v3);
        }
    } else {
#pragma unroll
      for (int m = 0; m < 4; ++m)
#pragma unroll
        for (int n = 0; n < 4; ++n)
#pragma unroll
          for (int r = 0; r < 4; ++r) {
            const int row = wr * 64 + m * 16 + fq * 4 + r;
            const int col = wc * 64 + n * 16 + fr;
            storeC(&C[(size_t)(m0 + row) * ldC + n0 + col], acc[m][n][r]);
          }
    }
  } else {
#pragma unroll
    for (int m = 0; m < 4; ++m) {
      const int row0 = m0 + wr * 64 + m * 16 + fq * 4;
      const int b = row0 >> 11, t0 = row0 & (T_SEQ - 1);
#pragma unroll
      for (int n = 0; n < 4; ++n) {
        const int vcol = n0 - 1280 + wc * 64 + n * 16 + fr;
        const int g = b * 4 + (vcol >> 6);
        const int d = vcol & 63;
        uint2 pk2;
        pk2.x = cvtpk(acc[m][n][0], acc[m][n][1]);
        pk2.y = cvtpk(acc[m][n][2], acc[m][n][3]);
        *(uint2*)(v_t + ((size_t)g * HD + d) * T_SEQ + t0) = pk2;
      }
    }
  }
}

// ---------------------------------------------------------------------------
// Causal GQA flash attention — REVERT to round-17 config (best measured:
// 80.1us). 8-wave split-k paired blocks, KVBLK=64: block = 4 strip-pairs x
// 2 split-k waves; wave parity h consumes subtile h of each 64-k round.
// Reg-staged cooperative LDS (XOR-swizzled, dbuf 32KB), grid 512 = 2
// blocks/CU. r18 (KVBLK=128: flat) and r19 (combined-SM+gll16: -9%)
// both regressed from this point.
// ---------------------------------------------------------------------------
__global__ __launch_bounds__(512) void attn(
    const bf16_t* __restrict__ qkv, const bf16_t* __restrict__ v_t,
    bf16_t* __restrict__ y)
{
  __shared__ int4 lds[2048];      // 32 KB: dbuf x (K 8KB + V 8KB)
  const int tid  = threadIdx.x;   // 0..511
  const int lane = tid & 63;
  const int w    = tid >> 6;      // 0..7
  const int spair= w >> 1;        // 0..3: strip within block
  const int h    = w & 1;         // split-k parity
  const int ql   = lane & 31;
  const int hi   = lane >> 5;
  const int id   = (int)blockIdx.x;          // 0..511
  const int low3 = id & 7;
  const int rest = id >> 3;                  // 0..63
  const int gsel = rest & 1;
  const int hh   = (rest >> 1) & 3;
  const int p    = rest >> 3;                // 0..7
  const int g16  = low3 + 8 * gsel;          // b*4+kvh (same-XCD clustering)
  const int b    = g16 >> 2, kvh = g16 & 3;
  const int hd   = kvh * 4 + hh;
  const int sA   = 4 * p + spair;            // pass-0 strip; pass-1 = 63-sA
  const float SCALE_LOG2 = 0.125f * 1.44269504089f;

  // staging: 512 threads cover both subtiles (u = tid>>8) of K and V
  const int sid = tid & 255;
  const int u   = tid >> 8;
  const int kr = sid >> 3, kslot = sid & 7;
  const int vd = sid >> 2, vslot = sid & 3;
  const bf16_t* gK = qkv + (size_t)(b * T_SEQ + kr + u * 32) * LDQKV + 1024 + kvh * HD + kslot * 8;
  const bf16_t* gV = v_t + (size_t)((b * N_KV + kvh) * HD + vd) * T_SEQ + vslot * 8 + u * 32;
  const int wKidx = u * 256 + kr * 8 + (kslot ^ (kr & 7));
  const int wVidx = 512 + u * 256 + vd * 4 + (vslot ^ ((vd >> 1) & 3));

  // fragment read indices (subtile-relative; + h*256 + buf*1024)
  int kridx[4];
#pragma unroll
  for (int c = 0; c < 4; ++c)
    kridx[c] = ql * 8 + ((2 * c + hi) ^ (ql & 7));
  const int vsw = (ql >> 1) & 3;
  const int v0idx = 512 + ql * 4 + (hi ^ vsw);
  const int v1idx = 512 + ql * 4 + ((2 + hi) ^ vsw);
  const int v2idx = 512 + (ql + 32) * 4 + (hi ^ vsw);
  const int v3idx = 512 + (ql + 32) * 4 + ((2 + hi) ^ vsw);

  union ob { unsigned uu[4]; bf16x8 v; } onesf;
#pragma unroll
  for (int i = 0; i < 4; ++i) onesf.uu[i] = 0x3F803F80u;

  f32x16 zro;
#pragma unroll
  for (int i = 0; i < 16; ++i) zro[i] = 0.f;

  float* lf = (float*)lds;
  int buf = 0;
#pragma unroll
  for (int pi = 0; pi < 2; ++pi) {
    const int s = pi ? (63 - sA) : sA;
    const int q_glob = s * 32 + ql;
    const int nt = s + 1;                              // strip's 32-k tiles
    const int nR = pi ? (32 - 2 * p) : (2 * p + 2);    // block-uniform rounds

    // Q fragments, pre-scaled into log2 domain (same for both pair waves)
    const bf16_t* Qrow = qkv + (size_t)(b * T_SEQ + q_glob) * LDQKV + hd * HD + hi * 8;
    bf16x8 qfrag[4];
#pragma unroll
    for (int c = 0; c < 4; ++c) {
      bf16x8 raw = *(const bf16x8*)(Qrow + c * 16);
      bf16x8 sc;
#pragma unroll
      for (int j = 0; j < 8; ++j)
        sc[j] = (__bf16)((float)raw[j] * SCALE_LOG2);
      qfrag[c] = sc;
    }

    f32x16 acc0, acc1, accL;
#pragma unroll
    for (int i = 0; i < 16; ++i) { acc0[i] = 0.f; acc1[i] = 0.f; accL[i] = 0.f; }
    float m_run = -1e30f;

    // prologue: stage round-0 pair into current buf
    {
      int4 kA = *(const int4*)gK;
      int4 vA = *(const int4*)gV;
      const int nb = buf * 1024;
      lds[nb + wKidx] = kA;
      lds[nb + wVidx] = vA;
    }
    __syncthreads();

    for (int r = 0; r < nR; ++r) {
      int4 kA, vA;
      const bool more = (r + 1 < nR);
      if (more) {
        kA = *(const int4*)(gK + (size_t)(r + 1) * 64 * LDQKV);
        vA = *(const int4*)(gV + (r + 1) * 64);
      }

      const int t = 2 * r + h;     // this wave's tile (parity split)
      if (t < nt) {
        const int k0 = t << 5;
        const bool masked = (t == nt - 1);
        const int base = buf * 1024 + h * 256;

        bf16x8 kf0 = *(const bf16x8*)&lds[base + kridx[0]];
        bf16x8 kf1 = *(const bf16x8*)&lds[base + kridx[1]];
        bf16x8 kf2 = *(const bf16x8*)&lds[base + kridx[2]];
        bf16x8 kf3 = *(const bf16x8*)&lds[base + kridx[3]];

        __builtin_amdgcn_s_setprio(1);
        f32x16 st = __builtin_amdgcn_mfma_f32_32x32x16_bf16(kf0, qfrag[0], zro, 0, 0, 0);
        st = __builtin_amdgcn_mfma_f32_32x32x16_bf16(kf1, qfrag[1], st, 0, 0, 0);
        st = __builtin_amdgcn_mfma_f32_32x32x16_bf16(kf2, qfrag[2], st, 0, 0, 0);
        st = __builtin_amdgcn_mfma_f32_32x32x16_bf16(kf3, qfrag[3], st, 0, 0, 0);
        __builtin_amdgcn_s_setprio(0);

        if (masked) {
#pragma unroll
          for (int rr = 0; rr < 16; ++rr) {
            const int kg = k0 + (rr & 3) + 8 * (rr >> 2) + 4 * hi;
            if (kg > q_glob) st[rr] = -1e30f;
          }
        }
        float m01 = fmaxf(fmaxf(st[0], st[1]), st[2]);
        float m02 = fmaxf(fmaxf(st[3], st[4]), st[5]);
        float m03 = fmaxf(fmaxf(st[6], st[7]), st[8]);
        float m04 = fmaxf(fmaxf(st[9], st[10]), st[11]);
        float m05 = fmaxf(fmaxf(st[12], st[13]), st[14]);
        float m06 = fmaxf(fmaxf(m01, m02), m03);
        float m07 = fmaxf(fmaxf(m04, m05), st[15]);
        const float bmax = fmaxf(m06, m07);
        if (__any(bmax > m_run + 8.f)) {        // T13 defer-max
          const float rmax = fmaxf(bmax, __shfl_xor(bmax, 32));
          const float mnew = fmaxf(m_run, rmax);
          const float corr = fexp2(m_run - mnew);
#pragma unroll
          for (int i = 0; i < 16; ++i) { acc0[i] *= corr; acc1[i] *= corr; }
          accL[0] *= corr;
          m_run = mnew;
        }
        float pp[16];
#pragma unroll
        for (int rr = 0; rr < 16; ++rr) pp[rr] = fexp2(st[rr] - m_run);

        unsigned wp[8];
#pragma unroll
        for (int i = 0; i < 8; ++i) wp[i] = cvtpk(pp[2 * i], pp[2 * i + 1]);
        plswap(wp[0], wp[2]); plswap(wp[1], wp[3]);
        plswap(wp[4], wp[6]); plswap(wp[5], wp[7]);
        union fu { unsigned uu2[4]; bf16x8 v; };
        fu f1, f2;
        f1.uu2[0] = wp[0]; f1.uu2[1] = wp[1]; f1.uu2[2] = wp[2]; f1.uu2[3] = wp[3];
        f2.uu2[0] = wp[4]; f2.uu2[1] = wp[5]; f2.uu2[2] = wp[6]; f2.uu2[3] = wp[7];

        bf16x8 vf0 = *(const bf16x8*)&lds[base + v0idx];
        bf16x8 vf1 = *(const bf16x8*)&lds[base + v1idx];
        bf16x8 vf2 = *(const bf16x8*)&lds[base + v2idx];
        bf16x8 vf3 = *(const bf16x8*)&lds[base + v3idx];

        __builtin_amdgcn_s_setprio(1);
        acc0 = __builtin_amdgcn_mfma_f32_32x32x16_bf16(vf0, f1.v, acc0, 0, 0, 0);
        acc0 = __builtin_amdgcn_mfma_f32_32x32x16_bf16(vf1, f2.v, acc0, 0, 0, 0);
        acc1 = __builtin_amdgcn_mfma_f32_32x32x16_bf16(vf2, f1.v, acc1, 0, 0, 0);
        acc1 = __builtin_amdgcn_mfma_f32_32x32x16_bf16(vf3, f2.v, acc1, 0, 0, 0);
        accL = __builtin_amdgcn_mfma_f32_32x32x16_bf16(onesf.v, f1.v, accL, 0, 0, 0);
        accL = __builtin_amdgcn_mfma_f32_32x32x16_bf16(onesf.v, f2.v, accL, 0, 0, 0);
        __builtin_amdgcn_s_setprio(0);
      }

      if (more) {
        const int nb = (buf ^ 1) * 1024;
        lds[nb + wKidx] = kA;
        lds[nb + wVidx] = vA;
      }
      __syncthreads();
      buf ^= 1;
    }

    // ---- split-k merge: h=1 publishes partials, h=0 merges & stores ----
    float cA = 1.f, cB = 0.f, l_mrg = 0.f;
    if (h == 1) {
      const int fb = spair * 1216 + lane * 19;
#pragma unroll
      for (int i = 0; i < 16; ++i) lf[fb + i] = acc0[i];
      lf[fb + 16] = m_run;
      lf[fb + 17] = accL[0];
    }
    __syncthreads();
    if (h == 0) {
      const int fb = spair * 1216 + lane * 19;
      const float mB = lf[fb + 16], lB = lf[fb + 17];
      const float mM = fmaxf(m_run, mB);
      cA = fexp2(m_run - mM);
      cB = fexp2(mB - mM);
      l_mrg = accL[0] * cA + lB * cB;
#pragma unroll
      for (int i = 0; i < 16; ++i) acc0[i] = acc0[i] * cA + lf[fb + i] * cB;
    }
    __syncthreads();
    if (h == 1) {
      const int fb2 = spair * 1088 + lane * 17;
#pragma unroll
      for (int i = 0; i < 16; ++i) lf[fb2 + i] = acc1[i];
    }
    __syncthreads();
    if (h == 0) {
      const int fb2 = spair * 1088 + lane * 17;
#pragma unroll
      for (int i = 0; i < 16; ++i) acc1[i] = acc1[i] * cA + lf[fb2 + i] * cB;
      const float inv = 1.f / l_mrg;
      bf16_t* yrow = y + (size_t)(b * T_SEQ + q_glob) * D_MODEL + hd * HD;
#pragma unroll
      for (int gg = 0; gg < 4; ++gg) {
        uint2 o0, o1;
        o0.x = cvtpk(acc0[4 * gg + 0] * inv, acc0[4 * gg + 1] * inv);
        o0.y = cvtpk(acc0[4 * gg + 2] * inv, acc0[4 * gg + 3] * inv);
        o1.x = cvtpk(acc1[4 * gg + 0] * inv, acc1[4 * gg + 1] * inv);
        o1.y = cvtpk(acc1[4 * gg + 2] * inv, acc1[4 * gg + 3] * inv);
        *(uint2*)(yrow + 8 * gg + 4 * hi)      = o0;
        *(uint2*)(yrow + 32 + 8 * gg + 4 * hi) = o1;
      }
    }
    __syncthreads();   // fence LDS reads before next pass's prologue writes
  }
}

// ---------------------------------------------------------------------------
extern "C" void kernel_launch(void* const* d_in, const int* in_sizes, int n_in,
                              void* d_out, int out_size, void* d_ws,
                              size_t ws_size, hipStream_t stream) {
  const float* x    = (const float*)d_in[0];
  const float* cosb = (const float*)d_in[1];
  const float* sinb = (const float*)d_in[2];
  const float* Wq   = (const float*)d_in[3];
  const float* Wk   = (const float*)d_in[4];
  const float* Wv   = (const float*)d_in[5];
  const float* Wo   = (const float*)d_in[6];
  const float* qs   = (const float*)d_in[7];
  const float* ks   = (const float*)d_in[8];
  float* out = (float*)d_out;   // reference output dtype is float32

  char* ws = (char*)d_ws;
  bf16_t* qkv   = (bf16_t*)ws;                       // 25165824 B
  bf16_t* v_t   = (bf16_t*)(ws + 25165824);          // 4194304 B
  bf16_t* y     = (bf16_t*)(ws + 29360128);          // 16777216 B (= xb alias)
  bf16_t* xb    = y;                                 // xb dead before attn writes y
  bf16_t* wqkvb = (bf16_t*)(ws + 46137344);          // 3145728 B
  bf16_t* wob   = (bf16_t*)(ws + 49283072);          // 2097152 B

  // 0. fp32 -> bf16 converts (one launch: x + all weights)
  all_cvt<<<dim3(2688), 256, 0, stream>>>(x, Wq, Wk, Wv, Wo, xb, wqkvb, wob);

  // 1. fused QKV projection + RMSNorm + RoPE + V-transpose
  gemm_bb<1, bf16_t><<<dim3(12, 64), 256, 0, stream>>>(
      xb, wqkvb, qkv, LDQKV, cosb, sinb, qs, ks, v_t);
  // 2. causal GQA flash attention -> y (8-wave split-k, KVBLK=64)
  attn<<<dim3(512), 512, 0, stream>>>(qkv, v_t, y);
  // 3. output projection
  gemm_bb<0, float><<<dim3(8, 64), 256, 0, stream>>>(
      y, wob, out, D_MODEL, nullptr, nullptr, nullptr, nullptr, nullptr);
}

// Round 21
// 152.867 us; speedup vs baseline: 1.0713x; 1.0490x over previous
//
#include <hip/hip_runtime.h>
#include <hip/hip_bf16.h>
#include <stdint.h>

typedef __attribute__((ext_vector_type(8)))  __bf16 bf16x8;
typedef __attribute__((ext_vector_type(4)))  float  f32x4;
typedef __attribute__((ext_vector_type(16))) float  f32x16;
typedef __hip_bfloat16 bf16_t;

#define T_SEQ 2048
#define D_MODEL 1024
#define N_HEADS 16
#define N_KV 4
#define HD 64
#define LDQKV 1536
#define KDIM 1024

// Convert 16 consecutive fp32 (4x float4) -> 16 bf16 (2x int4)
__device__ inline void cvt16(const float4* __restrict__ g, int4* __restrict__ s) {
  float4 v0 = g[0], v1 = g[1], v2 = g[2], v3 = g[3];
  union { int4 i[2]; __hip_bfloat162 h[8]; } u;
  u.h[0] = __float22bfloat162_rn(make_float2(v0.x, v0.y));
  u.h[1] = __float22bfloat162_rn(make_float2(v0.z, v0.w));
  u.h[2] = __float22bfloat162_rn(make_float2(v1.x, v1.y));
  u.h[3] = __float22bfloat162_rn(make_float2(v1.z, v1.w));
  u.h[4] = __float22bfloat162_rn(make_float2(v2.x, v2.y));
  u.h[5] = __float22bfloat162_rn(make_float2(v2.z, v2.w));
  u.h[6] = __float22bfloat162_rn(make_float2(v3.x, v3.y));
  u.h[7] = __float22bfloat162_rn(make_float2(v3.z, v3.w));
  s[0] = u.i[0]; s[1] = u.i[1];
}

__device__ inline void storeC(bf16_t* p, float v) { *p = __float2bfloat16(v); }
__device__ inline void storeC(float* p, float v) { *p = v; }

// v_permlane32_swap_b32 vdst, vsrc: after plswap(a,b): a={a_L,b_L}, b={a_U,b_U}
__device__ inline void plswap(unsigned& a, unsigned& b) {
  asm volatile("v_permlane32_swap_b32 %0, %1" : "+v"(a), "+v"(b));
}

// HW transcendental exp2 (input already in log2 domain)
__device__ inline float fexp2(float x) {
  float r; asm("v_exp_f32 %0, %1" : "=v"(r) : "v"(x)); return r;
}
// HW packed fp32->bf16 (T12 recipe; no builtin on gfx950)
__device__ inline unsigned cvtpk(float lo, float hi) {
  unsigned r; asm("v_cvt_pk_bf16_f32 %0, %1, %2" : "=v"(r) : "v"(lo), "v"(hi));
  return r;
}

// async global->LDS, 16B per lane; lds dest must be wave-uniform base.
__device__ inline void gll16(const bf16_t* g, bf16_t* l) {
  __builtin_amdgcn_global_load_lds(
      (const __attribute__((address_space(1))) void*)g,
      (__attribute__((address_space(3))) void*)l, 16, 0, 0);
}

// ---------------------------------------------------------------------------
// fp32 -> bf16 bulk convert, x + all weights in ONE launch (units of 16 elem)
// ---------------------------------------------------------------------------
__global__ __launch_bounds__(256) void all_cvt(
    const float* __restrict__ x,
    const float* __restrict__ Wq, const float* __restrict__ Wk,
    const float* __restrict__ Wv, const float* __restrict__ Wo,
    bf16_t* __restrict__ xb, bf16_t* __restrict__ wqkvb,
    bf16_t* __restrict__ wob) {
  const int i = blockIdx.x * 256 + threadIdx.x;
  const float* s; bf16_t* d; int off;
  if (i < 524288)      { s = x;  d = xb;                   off = i; }
  else if (i < 589824) { s = Wq; d = wqkvb;                off = i - 524288; }
  else if (i < 606208) { s = Wk; d = wqkvb + 1024 * 1024;  off = i - 589824; }
  else if (i < 622592) { s = Wv; d = wqkvb + 1280 * 1024;  off = i - 606208; }
  else                 { s = Wo; d = wob;                  off = i - 622592; }
  cvt16((const float4*)s + off * 4, (int4*)d + off * 2);
}

// ---------------------------------------------------------------------------
// GEMM bf16 x bf16 (passing, fused QKV epilogue)
// ---------------------------------------------------------------------------
template <int MODE, typename CT>
__global__ __launch_bounds__(256) void gemm_bb(
    const bf16_t* __restrict__ A, const bf16_t* __restrict__ W,
    CT* __restrict__ C, const int ldC,
    const float* __restrict__ cosb, const float* __restrict__ sinb,
    const float* __restrict__ qs, const float* __restrict__ ks,
    bf16_t* __restrict__ v_t)
{
  __shared__ bf16_t As[128 * 32];
  __shared__ bf16_t Bs[128 * 32];
  const int tid = threadIdx.x;
  const int lane = tid & 63;
  const int wv = tid >> 6;
  const int wr = wv >> 1, wc = wv & 1;
  const int m0 = blockIdx.y * 128;
  const int n0 = blockIdx.x * 128;

  const int srow = lane >> 2;
  const int scol = (lane & 3) * 8;
  const bf16_t* gA = A + (size_t)(m0 + 32 * wv + srow) * KDIM + scol;
  const bf16_t* gB = W + (size_t)(n0 + 32 * wv + srow) * KDIM + scol;
  bf16_t* lA = As + wv * 1024;
  bf16_t* lB = Bs + wv * 1024;

  f32x4 acc[4][4];
#pragma unroll
  for (int m = 0; m < 4; ++m)
#pragma unroll
    for (int n = 0; n < 4; ++n)
      acc[m][n] = {0.f, 0.f, 0.f, 0.f};

  const int fr = lane & 15;
  const int fq = lane >> 4;

  for (int k0 = 0; k0 < KDIM; k0 += 32) {
    gll16(gA + k0, lA);
    gll16(gA + 16 * KDIM + k0, lA + 512);
    gll16(gB + k0, lB);
    gll16(gB + 16 * KDIM + k0, lB + 512);
    __syncthreads();
    bf16x8 af[4], bfv[4];
#pragma unroll
    for (int m = 0; m < 4; ++m)
      af[m] = *(const bf16x8*)(&As[(wr * 64 + m * 16 + fr) * 32 + fq * 8]);
#pragma unroll
    for (int n = 0; n < 4; ++n)
      bfv[n] = *(const bf16x8*)(&Bs[(wc * 64 + n * 16 + fr) * 32 + fq * 8]);
#pragma unroll
    for (int m = 0; m < 4; ++m)
#pragma unroll
      for (int n = 0; n < 4; ++n)
        acc[m][n] = __builtin_amdgcn_mfma_f32_16x16x32_bf16(af[m], bfv[n],
                                                            acc[m][n], 0, 0, 0);
    __syncthreads();
  }

  if (MODE == 0 || n0 < 1280) {
    if (MODE == 1) {
      const float* stab = (n0 < 1024) ? qs : ks;
      float sc0 = stab[fr], sc1 = stab[16 + fr], sc2 = stab[32 + fr], sc3 = stab[48 + fr];
#pragma unroll
      for (int m = 0; m < 4; ++m)
#pragma unroll
        for (int r = 0; r < 4; ++r) {
          const int row = m0 + wr * 64 + m * 16 + fq * 4 + r;
          const int t = row & (T_SEQ - 1);
          float ss = acc[m][0][r] * acc[m][0][r] + acc[m][1][r] * acc[m][1][r]
                   + acc[m][2][r] * acc[m][2][r] + acc[m][3][r] * acc[m][3][r];
          ss += __shfl_xor(ss, 1);
          ss += __shfl_xor(ss, 2);
          ss += __shfl_xor(ss, 4);
          ss += __shfl_xor(ss, 8);
          const float nrm = rsqrtf(ss * (1.f / 64.f) + 1e-6f);
          const float v0 = acc[m][0][r] * nrm * sc0;
          const float v1 = acc[m][1][r] * nrm * sc1;
          const float v2 = acc[m][2][r] * nrm * sc2;
          const float v3 = acc[m][3][r] * nrm * sc3;
          const float c = cosb[t * 16 + fr];
          const float s = sinb[t * 16 + fr];
          const float r0 = v0 * c - v1 * s;
          const float r1 = v0 * s + v1 * c;
          bf16_t* p = (bf16_t*)C + (size_t)row * ldC + n0 + wc * 64 + fr;
          p[0]  = __float2bfloat16(r0);
          p[16] = __float2bfloat16(r1);
          p[32] = __float2bfloat16(v2);
          p[48] = __float2bfloat16(v3);
        }
    } else {
#pragma unroll
      for (int m = 0; m < 4; ++m)
#pragma unroll
        for (int n = 0; n < 4; ++n)
#pragma unroll
          for (int r = 0; r < 4; ++r) {
            const int row = wr * 64 + m * 16 + fq * 4 + r;
            const int col = wc * 64 + n * 16 + fr;
            storeC(&C[(size_t)(m0 + row) * ldC + n0 + col], acc[m][n][r]);
          }
    }
  } else {
#pragma unroll
    for (int m = 0; m < 4; ++m) {
      const int row0 = m0 + wr * 64 + m * 16 + fq * 4;
      const int b = row0 >> 11, t0 = row0 & (T_SEQ - 1);
#pragma unroll
      for (int n = 0; n < 4; ++n) {
        const int vcol = n0 - 1280 + wc * 64 + n * 16 + fr;
        const int g = b * 4 + (vcol >> 6);
        const int d = vcol & 63;
        uint2 pk2;
        pk2.x = cvtpk(acc[m][n][0], acc[m][n][1]);
        pk2.y = cvtpk(acc[m][n][2], acc[m][n][3]);
        *(uint2*)(v_t + ((size_t)g * HD + d) * T_SEQ + t0) = pk2;
      }
    }
  }
}

// ---------------------------------------------------------------------------
// Causal GQA flash attention v16 — UNPAIRED strips, quad blocks.
// Block = 8 waves = 4 single strips (quad {4*sb..4*sb+3}) x split-k-2; ONE
// pass per wave (no pairing). Grid 1024 = 4 blocks/CU; r10's balanced
// permutation equalizes per-CU round sums (CU class id&255 gets quads
// {q,q+4,q+8,q+12}, round sums 2*30+8=68 = r17's 2x34). Residency rises
// 16 -> ~24 waves/CU (VGPR-capped). Per-tile math, staging, swizzles and
// split-k merge byte-identical to r17/r20 (passing, 79.5us).
// ---------------------------------------------------------------------------
__global__ __launch_bounds__(512) void attn(
    const bf16_t* __restrict__ qkv, const bf16_t* __restrict__ v_t,
    bf16_t* __restrict__ y)
{
  __shared__ int4 lds[2048];      // 32 KB: dbuf x (K 8KB + V 8KB)
  const int tid  = threadIdx.x;   // 0..511
  const int lane = tid & 63;
  const int w    = tid >> 6;      // 0..7
  const int spair= w >> 1;        // 0..3: strip within quad
  const int h    = w & 1;         // split-k parity
  const int ql   = lane & 31;
  const int hi   = lane >> 5;
  const int id   = (int)blockIdx.x;          // 0..1023
  const int low3 = id & 7;
  const int rest = id >> 3;                  // 0..127
  const int gsel = rest & 1;
  const int hh   = (rest >> 1) & 3;
  const int sbi  = rest >> 3;                // 0..15: quad index (pre-perm)
  // balanced permutation (r10): CU class {m,m+4,m+8,m+12} -> quad sums 30.
  const int sb   = ((sbi >> 2) & 1) ? (sbi + 4 - ((sbi >> 3) << 4)) : (15 - sbi);
  const int g16  = low3 + 8 * gsel;          // b*4+kvh (same-XCD clustering)
  const int b    = g16 >> 2, kvh = g16 & 3;
  const int hd   = kvh * 4 + hh;
  const int s    = 4 * sb + spair;           // this wave's single strip
  const int q_glob = s * 32 + ql;
  const int nt   = s + 1;                    // strip's 32-k tiles
  const int nR   = 2 * sb + 2;               // block-uniform 64-k rounds
  const float SCALE_LOG2 = 0.125f * 1.44269504089f;

  // staging: 512 threads cover both subtiles (u = tid>>8) of K and V
  const int sid = tid & 255;
  const int u   = tid >> 8;
  const int kr = sid >> 3, kslot = sid & 7;
  const int vd = sid >> 2, vslot = sid & 3;
  const bf16_t* gK = qkv + (size_t)(b * T_SEQ + kr + u * 32) * LDQKV + 1024 + kvh * HD + kslot * 8;
  const bf16_t* gV = v_t + (size_t)((b * N_KV + kvh) * HD + vd) * T_SEQ + vslot * 8 + u * 32;
  const int wKidx = u * 256 + kr * 8 + (kslot ^ (kr & 7));
  const int wVidx = 512 + u * 256 + vd * 4 + (vslot ^ ((vd >> 1) & 3));

  // fragment read indices (subtile-relative; + h*256 + buf*1024)
  int kridx[4];
#pragma unroll
  for (int c = 0; c < 4; ++c)
    kridx[c] = ql * 8 + ((2 * c + hi) ^ (ql & 7));
  const int vsw = (ql >> 1) & 3;
  const int v0idx = 512 + ql * 4 + (hi ^ vsw);
  const int v1idx = 512 + ql * 4 + ((2 + hi) ^ vsw);
  const int v2idx = 512 + (ql + 32) * 4 + (hi ^ vsw);
  const int v3idx = 512 + (ql + 32) * 4 + ((2 + hi) ^ vsw);

  union ob { unsigned uu[4]; bf16x8 v; } onesf;
#pragma unroll
  for (int i = 0; i < 4; ++i) onesf.uu[i] = 0x3F803F80u;

  f32x16 zro;
#pragma unroll
  for (int i = 0; i < 16; ++i) zro[i] = 0.f;

  float* lf = (float*)lds;

  // Q fragments, pre-scaled into log2 domain (same for both pair waves)
  const bf16_t* Qrow = qkv + (size_t)(b * T_SEQ + q_glob) * LDQKV + hd * HD + hi * 8;
  bf16x8 qfrag[4];
#pragma unroll
  for (int c = 0; c < 4; ++c) {
    bf16x8 raw = *(const bf16x8*)(Qrow + c * 16);
    bf16x8 sc;
#pragma unroll
    for (int j = 0; j < 8; ++j)
      sc[j] = (__bf16)((float)raw[j] * SCALE_LOG2);
    qfrag[c] = sc;
  }

  f32x16 acc0, acc1, accL;
#pragma unroll
  for (int i = 0; i < 16; ++i) { acc0[i] = 0.f; acc1[i] = 0.f; accL[i] = 0.f; }
  float m_run = -1e30f;

  // prologue: stage round-0 pair into buf 0
  {
    int4 kA = *(const int4*)gK;
    int4 vA = *(const int4*)gV;
    lds[wKidx] = kA;
    lds[wVidx] = vA;
  }
  __syncthreads();

  int buf = 0;
  for (int r = 0; r < nR; ++r) {
    int4 kA, vA;
    const bool more = (r + 1 < nR);
    if (more) {
      kA = *(const int4*)(gK + (size_t)(r + 1) * 64 * LDQKV);
      vA = *(const int4*)(gV + (r + 1) * 64);
    }

    const int t = 2 * r + h;     // this wave's tile (parity split)
    if (t < nt) {
      const int k0 = t << 5;
      const bool masked = (t == nt - 1);
      const int base = buf * 1024 + h * 256;

      bf16x8 kf0 = *(const bf16x8*)&lds[base + kridx[0]];
      bf16x8 kf1 = *(const bf16x8*)&lds[base + kridx[1]];
      bf16x8 kf2 = *(const bf16x8*)&lds[base + kridx[2]];
      bf16x8 kf3 = *(const bf16x8*)&lds[base + kridx[3]];

      __builtin_amdgcn_s_setprio(1);
      f32x16 st = __builtin_amdgcn_mfma_f32_32x32x16_bf16(kf0, qfrag[0], zro, 0, 0, 0);
      st = __builtin_amdgcn_mfma_f32_32x32x16_bf16(kf1, qfrag[1], st, 0, 0, 0);
      st = __builtin_amdgcn_mfma_f32_32x32x16_bf16(kf2, qfrag[2], st, 0, 0, 0);
      st = __builtin_amdgcn_mfma_f32_32x32x16_bf16(kf3, qfrag[3], st, 0, 0, 0);
      __builtin_amdgcn_s_setprio(0);

      if (masked) {
#pragma unroll
        for (int rr = 0; rr < 16; ++rr) {
          const int kg = k0 + (rr & 3) + 8 * (rr >> 2) + 4 * hi;
          if (kg > q_glob) st[rr] = -1e30f;
        }
      }
      float m01 = fmaxf(fmaxf(st[0], st[1]), st[2]);
      float m02 = fmaxf(fmaxf(st[3], st[4]), st[5]);
      float m03 = fmaxf(fmaxf(st[6], st[7]), st[8]);
      float m04 = fmaxf(fmaxf(st[9], st[10]), st[11]);
      float m05 = fmaxf(fmaxf(st[12], st[13]), st[14]);
      float m06 = fmaxf(fmaxf(m01, m02), m03);
      float m07 = fmaxf(fmaxf(m04, m05), st[15]);
      const float bmax = fmaxf(m06, m07);
      if (__any(bmax > m_run + 8.f)) {        // T13 defer-max
        const float rmax = fmaxf(bmax, __shfl_xor(bmax, 32));
        const float mnew = fmaxf(m_run, rmax);
        const float corr = fexp2(m_run - mnew);
#pragma unroll
        for (int i = 0; i < 16; ++i) { acc0[i] *= corr; acc1[i] *= corr; }
        accL[0] *= corr;
        m_run = mnew;
      }
      float pp[16];
#pragma unroll
      for (int rr = 0; rr < 16; ++rr) pp[rr] = fexp2(st[rr] - m_run);

      unsigned wp[8];
#pragma unroll
      for (int i = 0; i < 8; ++i) wp[i] = cvtpk(pp[2 * i], pp[2 * i + 1]);
      plswap(wp[0], wp[2]); plswap(wp[1], wp[3]);
      plswap(wp[4], wp[6]); plswap(wp[5], wp[7]);
      union fu { unsigned uu2[4]; bf16x8 v; };
      fu f1, f2;
      f1.uu2[0] = wp[0]; f1.uu2[1] = wp[1]; f1.uu2[2] = wp[2]; f1.uu2[3] = wp[3];
      f2.uu2[0] = wp[4]; f2.uu2[1] = wp[5]; f2.uu2[2] = wp[6]; f2.uu2[3] = wp[7];

      bf16x8 vf0 = *(const bf16x8*)&lds[base + v0idx];
      bf16x8 vf1 = *(const bf16x8*)&lds[base + v1idx];
      bf16x8 vf2 = *(const bf16x8*)&lds[base + v2idx];
      bf16x8 vf3 = *(const bf16x8*)&lds[base + v3idx];

      __builtin_amdgcn_s_setprio(1);
      acc0 = __builtin_amdgcn_mfma_f32_32x32x16_bf16(vf0, f1.v, acc0, 0, 0, 0);
      acc0 = __builtin_amdgcn_mfma_f32_32x32x16_bf16(vf1, f2.v, acc0, 0, 0, 0);
      acc1 = __builtin_amdgcn_mfma_f32_32x32x16_bf16(vf2, f1.v, acc1, 0, 0, 0);
      acc1 = __builtin_amdgcn_mfma_f32_32x32x16_bf16(vf3, f2.v, acc1, 0, 0, 0);
      accL = __builtin_amdgcn_mfma_f32_32x32x16_bf16(onesf.v, f1.v, accL, 0, 0, 0);
      accL = __builtin_amdgcn_mfma_f32_32x32x16_bf16(onesf.v, f2.v, accL, 0, 0, 0);
      __builtin_amdgcn_s_setprio(0);
    }

    if (more) {
      const int nb = (buf ^ 1) * 1024;
      lds[nb + wKidx] = kA;
      lds[nb + wVidx] = vA;
    }
    __syncthreads();
    buf ^= 1;
  }

  // ---- split-k merge: h=1 publishes partials, h=0 merges & stores ----
  float cA = 1.f, cB = 0.f, l_mrg = 0.f;
  if (h == 1) {
    const int fb = spair * 1216 + lane * 19;
#pragma unroll
    for (int i = 0; i < 16; ++i) lf[fb + i] = acc0[i];
    lf[fb + 16] = m_run;
    lf[fb + 17] = accL[0];
  }
  __syncthreads();
  if (h == 0) {
    const int fb = spair * 1216 + lane * 19;
    const float mB = lf[fb + 16], lB = lf[fb + 17];
    const float mM = fmaxf(m_run, mB);
    cA = fexp2(m_run - mM);
    cB = fexp2(mB - mM);
    l_mrg = accL[0] * cA + lB * cB;
#pragma unroll
    for (int i = 0; i < 16; ++i) acc0[i] = acc0[i] * cA + lf[fb + i] * cB;
  }
  __syncthreads();
  if (h == 1) {
    const int fb2 = spair * 1088 + lane * 17;
#pragma unroll
    for (int i = 0; i < 16; ++i) lf[fb2 + i] = acc1[i];
  }
  __syncthreads();
  if (h == 0) {
    const int fb2 = spair * 1088 + lane * 17;
#pragma unroll
    for (int i = 0; i < 16; ++i) acc1[i] = acc1[i] * cA + lf[fb2 + i] * cB;
    const float inv = 1.f / l_mrg;
    bf16_t* yrow = y + (size_t)(b * T_SEQ + q_glob) * D_MODEL + hd * HD;
#pragma unroll
    for (int gg = 0; gg < 4; ++gg) {
      uint2 o0, o1;
      o0.x = cvtpk(acc0[4 * gg + 0] * inv, acc0[4 * gg + 1] * inv);
      o0.y = cvtpk(acc0[4 * gg + 2] * inv, acc0[4 * gg + 3] * inv);
      o1.x = cvtpk(acc1[4 * gg + 0] * inv, acc1[4 * gg + 1] * inv);
      o1.y = cvtpk(acc1[4 * gg + 2] * inv, acc1[4 * gg + 3] * inv);
      *(uint2*)(yrow + 8 * gg + 4 * hi)      = o0;
      *(uint2*)(yrow + 32 + 8 * gg + 4 * hi) = o1;
    }
  }
}

// ---------------------------------------------------------------------------
extern "C" void kernel_launch(void* const* d_in, const int* in_sizes, int n_in,
                              void* d_out, int out_size, void* d_ws,
                              size_t ws_size, hipStream_t stream) {
  const float* x    = (const float*)d_in[0];
  const float* cosb = (const float*)d_in[1];
  const float* sinb = (const float*)d_in[2];
  const float* Wq   = (const float*)d_in[3];
  const float* Wk   = (const float*)d_in[4];
  const float* Wv   = (const float*)d_in[5];
  const float* Wo   = (const float*)d_in[6];
  const float* qs   = (const float*)d_in[7];
  const float* ks   = (const float*)d_in[8];
  float* out = (float*)d_out;   // reference output dtype is float32

  char* ws = (char*)d_ws;
  bf16_t* qkv   = (bf16_t*)ws;                       // 25165824 B
  bf16_t* v_t   = (bf16_t*)(ws + 25165824);          // 4194304 B
  bf16_t* y     = (bf16_t*)(ws + 29360128);          // 16777216 B (= xb alias)
  bf16_t* xb    = y;                                 // xb dead before attn writes y
  bf16_t* wqkvb = (bf16_t*)(ws + 46137344);          // 3145728 B
  bf16_t* wob   = (bf16_t*)(ws + 49283072);          // 2097152 B

  // 0. fp32 -> bf16 converts (one launch: x + all weights)
  all_cvt<<<dim3(2688), 256, 0, stream>>>(x, Wq, Wk, Wv, Wo, xb, wqkvb, wob);

  // 1. fused QKV projection + RMSNorm + RoPE + V-transpose
  gemm_bb<1, bf16_t><<<dim3(12, 64), 256, 0, stream>>>(
      xb, wqkvb, qkv, LDQKV, cosb, sinb, qs, ks, v_t);
  // 2. causal GQA flash attention -> y (unpaired quad blocks, grid 1024)
  attn<<<dim3(1024), 512, 0, stream>>>(qkv, v_t, y);
  // 3. output projection
  gemm_bb<0, float><<<dim3(8, 64), 256, 0, stream>>>(
      y, wob, out, D_MODEL, nullptr, nullptr, nullptr, nullptr, nullptr);
}

// Round 22
// 149.305 us; speedup vs baseline: 1.0968x; 1.0239x over previous
//
#include <hip/hip_runtime.h>
#include <hip/hip_bf16.h>
#include <stdint.h>

typedef __attribute__((ext_vector_type(8)))  __bf16 bf16x8;
typedef __attribute__((ext_vector_type(4)))  float  f32x4;
typedef __attribute__((ext_vector_type(16))) float  f32x16;
typedef __hip_bfloat16 bf16_t;

#define T_SEQ 2048
#define D_MODEL 1024
#define N_HEADS 16
#define N_KV 4
#define HD 64
#define LDQKV 1536
#define KDIM 1024

// Convert 16 consecutive fp32 (4x float4) -> 16 bf16 (2x int4)
__device__ inline void cvt16(const float4* __restrict__ g, int4* __restrict__ s) {
  float4 v0 = g[0], v1 = g[1], v2 = g[2], v3 = g[3];
  union { int4 i[2]; __hip_bfloat162 h[8]; } u;
  u.h[0] = __float22bfloat162_rn(make_float2(v0.x, v0.y));
  u.h[1] = __float22bfloat162_rn(make_float2(v0.z, v0.w));
  u.h[2] = __float22bfloat162_rn(make_float2(v1.x, v1.y));
  u.h[3] = __float22bfloat162_rn(make_float2(v1.z, v1.w));
  u.h[4] = __float22bfloat162_rn(make_float2(v2.x, v2.y));
  u.h[5] = __float22bfloat162_rn(make_float2(v2.z, v2.w));
  u.h[6] = __float22bfloat162_rn(make_float2(v3.x, v3.y));
  u.h[7] = __float22bfloat162_rn(make_float2(v3.z, v3.w));
  s[0] = u.i[0]; s[1] = u.i[1];
}

__device__ inline void storeC(bf16_t* p, float v) { *p = __float2bfloat16(v); }
__device__ inline void storeC(float* p, float v) { *p = v; }

// v_permlane32_swap_b32 vdst, vsrc: after plswap(a,b): a={a_L,b_L}, b={a_U,b_U}
__device__ inline void plswap(unsigned& a, unsigned& b) {
  asm volatile("v_permlane32_swap_b32 %0, %1" : "+v"(a), "+v"(b));
}

// HW transcendental exp2 (input already in log2 domain)
__device__ inline float fexp2(float x) {
  float r; asm("v_exp_f32 %0, %1" : "=v"(r) : "v"(x)); return r;
}
// HW packed fp32->bf16 (T12 recipe; no builtin on gfx950)
__device__ inline unsigned cvtpk(float lo, float hi) {
  unsigned r; asm("v_cvt_pk_bf16_f32 %0, %1, %2" : "=v"(r) : "v"(lo), "v"(hi));
  return r;
}

// async global->LDS, 16B per lane; lds dest must be wave-uniform base.
__device__ inline void gll16(const bf16_t* g, bf16_t* l) {
  __builtin_amdgcn_global_load_lds(
      (const __attribute__((address_space(1))) void*)g,
      (__attribute__((address_space(3))) void*)l, 16, 0, 0);
}

// ---------------------------------------------------------------------------
// fp32 -> bf16 bulk convert, x + all weights in ONE launch (units of 16 elem)
// ---------------------------------------------------------------------------
__global__ __launch_bounds__(256) void all_cvt(
    const float* __restrict__ x,
    const float* __restrict__ Wq, const float* __restrict__ Wk,
    const float* __restrict__ Wv, const float* __restrict__ Wo,
    bf16_t* __restrict__ xb, bf16_t* __restrict__ wqkvb,
    bf16_t* __restrict__ wob) {
  const int i = blockIdx.x * 256 + threadIdx.x;
  const float* s; bf16_t* d; int off;
  if (i < 524288)      { s = x;  d = xb;                   off = i; }
  else if (i < 589824) { s = Wq; d = wqkvb;                off = i - 524288; }
  else if (i < 606208) { s = Wk; d = wqkvb + 1024 * 1024;  off = i - 589824; }
  else if (i < 622592) { s = Wv; d = wqkvb + 1280 * 1024;  off = i - 606208; }
  else                 { s = Wo; d = wob;                  off = i - 622592; }
  cvt16((const float4*)s + off * 4, (int4*)d + off * 2);
}

// ---------------------------------------------------------------------------
// GEMM bf16 x bf16, m97 structure. NEW in r22:
//  * XCD panel clustering: 1-D grid, id&7 = m_panel&7, so all NX n-tiles of
//    one m-panel land on one XCD (A-panel fetched once per L2).
//  * MODE=1 v-blocks: epilogue transposes through LDS (XOR-swizzled) so v_t
//    stores are 32B-contiguous (was 8B at 4KB stride -> 64-way line splits).
//  * cvtpk for epilogue bf16 conversion (kills manual RNE VALU chains).
// ---------------------------------------------------------------------------
template <int MODE, int NX, typename CT>
__global__ __launch_bounds__(256) void gemm_bb(
    const bf16_t* __restrict__ A, const bf16_t* __restrict__ W,
    CT* __restrict__ C, const int ldC,
    const float* __restrict__ cosb, const float* __restrict__ sinb,
    const float* __restrict__ qs, const float* __restrict__ ks,
    bf16_t* __restrict__ v_t)
{
  __shared__ bf16_t Smem[8192];         // 16 KB: As | Bs; reused by v-epilogue
  bf16_t* As = Smem;
  bf16_t* Bs = Smem + 4096;
  const int tid = threadIdx.x;
  const int lane = tid & 63;
  const int wv = tid >> 6;
  const int wr = wv >> 1, wc = wv & 1;
  // XCD-clustered decode: id&7 == m_panel&7 under round-robin dispatch.
  const int id  = (int)blockIdx.x;
  const int xcd = id & 7;
  const int seq = id >> 3;
  const int mp  = (seq / NX) * 8 + xcd;
  const int nt  = seq - (seq / NX) * NX;
  const int m0 = mp * 128;
  const int n0 = nt * 128;

  const int srow = lane >> 2;
  const int scol = (lane & 3) * 8;
  const bf16_t* gA = A + (size_t)(m0 + 32 * wv + srow) * KDIM + scol;
  const bf16_t* gB = W + (size_t)(n0 + 32 * wv + srow) * KDIM + scol;
  bf16_t* lA = As + wv * 1024;
  bf16_t* lB = Bs + wv * 1024;

  f32x4 acc[4][4];
#pragma unroll
  for (int m = 0; m < 4; ++m)
#pragma unroll
    for (int n = 0; n < 4; ++n)
      acc[m][n] = {0.f, 0.f, 0.f, 0.f};

  const int fr = lane & 15;
  const int fq = lane >> 4;

  for (int k0 = 0; k0 < KDIM; k0 += 32) {
    gll16(gA + k0, lA);
    gll16(gA + 16 * KDIM + k0, lA + 512);
    gll16(gB + k0, lB);
    gll16(gB + 16 * KDIM + k0, lB + 512);
    __syncthreads();
    bf16x8 af[4], bfv[4];
#pragma unroll
    for (int m = 0; m < 4; ++m)
      af[m] = *(const bf16x8*)(&As[(wr * 64 + m * 16 + fr) * 32 + fq * 8]);
#pragma unroll
    for (int n = 0; n < 4; ++n)
      bfv[n] = *(const bf16x8*)(&Bs[(wc * 64 + n * 16 + fr) * 32 + fq * 8]);
#pragma unroll
    for (int m = 0; m < 4; ++m)
#pragma unroll
      for (int n = 0; n < 4; ++n)
        acc[m][n] = __builtin_amdgcn_mfma_f32_16x16x32_bf16(af[m], bfv[n],
                                                            acc[m][n], 0, 0, 0);
    __syncthreads();
  }

  if (MODE == 0 || n0 < 1280) {
    if (MODE == 1) {
      const float* stab = (n0 < 1024) ? qs : ks;
      float sc0 = stab[fr], sc1 = stab[16 + fr], sc2 = stab[32 + fr], sc3 = stab[48 + fr];
#pragma unroll
      for (int m = 0; m < 4; ++m)
#pragma unroll
        for (int r = 0; r < 4; ++r) {
          const int row = m0 + wr * 64 + m * 16 + fq * 4 + r;
          const int t = row & (T_SEQ - 1);
          float ss = acc[m][0][r] * acc[m][0][r] + acc[m][1][r] * acc[m][1][r]
                   + acc[m][2][r] * acc[m][2][r] + acc[m][3][r] * acc[m][3][r];
          ss += __shfl_xor(ss, 1);
          ss += __shfl_xor(ss, 2);
          ss += __shfl_xor(ss, 4);
          ss += __shfl_xor(ss, 8);
          const float nrm = rsqrtf(ss * (1.f / 64.f) + 1e-6f);
          const float v0 = acc[m][0][r] * nrm * sc0;
          const float v1 = acc[m][1][r] * nrm * sc1;
          const float v2 = acc[m][2][r] * nrm * sc2;
          const float v3 = acc[m][3][r] * nrm * sc3;
          const float c = cosb[t * 16 + fr];
          const float s = sinb[t * 16 + fr];
          union { unsigned u; bf16_t hh[2]; } pa, pb;
          pa.u = cvtpk(v0 * c - v1 * s, v0 * s + v1 * c);
          pb.u = cvtpk(v2, v3);
          bf16_t* p = (bf16_t*)C + (size_t)row * ldC + n0 + wc * 64 + fr;
          p[0]  = pa.hh[0];
          p[16] = pa.hh[1];
          p[32] = pb.hh[0];
          p[48] = pb.hh[1];
        }
    } else {
#pragma unroll
      for (int m = 0; m < 4; ++m)
#pragma unroll
        for (int n = 0; n < 4; ++n)
#pragma unroll
          for (int r = 0; r < 4; ++r) {
            const int row = wr * 64 + m * 16 + fq * 4 + r;
            const int col = wc * 64 + n * 16 + fr;
            storeC(&C[(size_t)(m0 + row) * ldC + n0 + col], acc[m][n][r]);
          }
    }
  } else {
    // v blocks: coalesced transposed store via LDS. Tile rows = 128 t (one
    // b), cols = 128 vcols. Two t-halves of 64 (by wr); LDS [64][128] bf16
    // with col XOR-swizzle (((t>>2)&7)<<4) -> conflict-free writes & reads.
    const int b4 = (m0 >> 11) * 4;
    const int t0base = m0 & (T_SEQ - 1);
    const int vcol = tid & 127;
    const int vc = n0 - 1280 + vcol;
    const int g = b4 + (vc >> 6);
    const int d = vc & 63;
#pragma unroll
    for (int half = 0; half < 2; ++half) {
      if (wr == half) {
#pragma unroll
        for (int m = 0; m < 4; ++m)
#pragma unroll
          for (int n = 0; n < 4; ++n)
#pragma unroll
            for (int r2 = 0; r2 < 4; r2 += 2) {
              union { unsigned u; bf16_t hh[2]; } pk2;
              pk2.u = cvtpk(acc[m][n][r2], acc[m][n][r2 + 1]);
              const int tl0 = m * 16 + fq * 4 + r2;
              const int col = wc * 64 + n * 16 + fr;
              const int sw = ((tl0 >> 2) & 7) << 4;   // same for tl0, tl0+1
              Smem[tl0 * 128 + (col ^ sw)]       = pk2.hh[0];
              Smem[(tl0 + 1) * 128 + (col ^ sw)] = pk2.hh[1];
            }
      }
      __syncthreads();
      bf16_t* dst0 = v_t + ((size_t)(g * HD + d)) * T_SEQ + t0base + half * 64;
#pragma unroll
      for (int ci = 0; ci < 2; ++ci) {
        const int cu = (tid >> 7) + ci * 2;           // chunk 0..3 (16 t each)
        union { int4 q[2]; bf16_t hh[16]; } ld;
#pragma unroll
        for (int t = 0; t < 16; ++t) {
          const int tt = cu * 16 + t;
          ld.hh[t] = Smem[tt * 128 + (vcol ^ (((tt >> 2) & 7) << 4))];
        }
        *(int4*)(dst0 + cu * 16)     = ld.q[0];
        *(int4*)(dst0 + cu * 16 + 8) = ld.q[1];
      }
      __syncthreads();
    }
  }
}

// ---------------------------------------------------------------------------
// Causal GQA flash attention v16 (unchanged from r21 — passing): unpaired
// strips, quad blocks, split-k-2, balanced permutation, grid 1024.
// ---------------------------------------------------------------------------
__global__ __launch_bounds__(512) void attn(
    const bf16_t* __restrict__ qkv, const bf16_t* __restrict__ v_t,
    bf16_t* __restrict__ y)
{
  __shared__ int4 lds[2048];      // 32 KB: dbuf x (K 8KB + V 8KB)
  const int tid  = threadIdx.x;   // 0..511
  const int lane = tid & 63;
  const int w    = tid >> 6;      // 0..7
  const int spair= w >> 1;        // 0..3: strip within quad
  const int h    = w & 1;         // split-k parity
  const int ql   = lane & 31;
  const int hi   = lane >> 5;
  const int id   = (int)blockIdx.x;          // 0..1023
  const int low3 = id & 7;
  const int rest = id >> 3;                  // 0..127
  const int gsel = rest & 1;
  const int hh   = (rest >> 1) & 3;
  const int sbi  = rest >> 3;                // 0..15: quad index (pre-perm)
  const int sb   = ((sbi >> 2) & 1) ? (sbi + 4 - ((sbi >> 3) << 4)) : (15 - sbi);
  const int g16  = low3 + 8 * gsel;          // b*4+kvh (same-XCD clustering)
  const int b    = g16 >> 2, kvh = g16 & 3;
  const int hd   = kvh * 4 + hh;
  const int s    = 4 * sb + spair;           // this wave's single strip
  const int q_glob = s * 32 + ql;
  const int nt   = s + 1;                    // strip's 32-k tiles
  const int nR   = 2 * sb + 2;               // block-uniform 64-k rounds
  const float SCALE_LOG2 = 0.125f * 1.44269504089f;

  const int sid = tid & 255;
  const int u   = tid >> 8;
  const int kr = sid >> 3, kslot = sid & 7;
  const int vd = sid >> 2, vslot = sid & 3;
  const bf16_t* gK = qkv + (size_t)(b * T_SEQ + kr + u * 32) * LDQKV + 1024 + kvh * HD + kslot * 8;
  const bf16_t* gV = v_t + (size_t)((b * N_KV + kvh) * HD + vd) * T_SEQ + vslot * 8 + u * 32;
  const int wKidx = u * 256 + kr * 8 + (kslot ^ (kr & 7));
  const int wVidx = 512 + u * 256 + vd * 4 + (vslot ^ ((vd >> 1) & 3));

  int kridx[4];
#pragma unroll
  for (int c = 0; c < 4; ++c)
    kridx[c] = ql * 8 + ((2 * c + hi) ^ (ql & 7));
  const int vsw = (ql >> 1) & 3;
  const int v0idx = 512 + ql * 4 + (hi ^ vsw);
  const int v1idx = 512 + ql * 4 + ((2 + hi) ^ vsw);
  const int v2idx = 512 + (ql + 32) * 4 + (hi ^ vsw);
  const int v3idx = 512 + (ql + 32) * 4 + ((2 + hi) ^ vsw);

  union ob { unsigned uu[4]; bf16x8 v; } onesf;
#pragma unroll
  for (int i = 0; i < 4; ++i) onesf.uu[i] = 0x3F803F80u;

  f32x16 zro;
#pragma unroll
  for (int i = 0; i < 16; ++i) zro[i] = 0.f;

  float* lf = (float*)lds;

  const bf16_t* Qrow = qkv + (size_t)(b * T_SEQ + q_glob) * LDQKV + hd * HD + hi * 8;
  bf16x8 qfrag[4];
#pragma unroll
  for (int c = 0; c < 4; ++c) {
    bf16x8 raw = *(const bf16x8*)(Qrow + c * 16);
    bf16x8 sc;
#pragma unroll
    for (int j = 0; j < 8; ++j)
      sc[j] = (__bf16)((float)raw[j] * SCALE_LOG2);
    qfrag[c] = sc;
  }

  f32x16 acc0, acc1, accL;
#pragma unroll
  for (int i = 0; i < 16; ++i) { acc0[i] = 0.f; acc1[i] = 0.f; accL[i] = 0.f; }
  float m_run = -1e30f;

  {
    int4 kA = *(const int4*)gK;
    int4 vA = *(const int4*)gV;
    lds[wKidx] = kA;
    lds[wVidx] = vA;
  }
  __syncthreads();

  int buf = 0;
  for (int r = 0; r < nR; ++r) {
    int4 kA, vA;
    const bool more = (r + 1 < nR);
    if (more) {
      kA = *(const int4*)(gK + (size_t)(r + 1) * 64 * LDQKV);
      vA = *(const int4*)(gV + (r + 1) * 64);
    }

    const int t = 2 * r + h;     // this wave's tile (parity split)
    if (t < nt) {
      const int k0 = t << 5;
      const bool masked = (t == nt - 1);
      const int base = buf * 1024 + h * 256;

      bf16x8 kf0 = *(const bf16x8*)&lds[base + kridx[0]];
      bf16x8 kf1 = *(const bf16x8*)&lds[base + kridx[1]];
      bf16x8 kf2 = *(const bf16x8*)&lds[base + kridx[2]];
      bf16x8 kf3 = *(const bf16x8*)&lds[base + kridx[3]];

      __builtin_amdgcn_s_setprio(1);
      f32x16 st = __builtin_amdgcn_mfma_f32_32x32x16_bf16(kf0, qfrag[0], zro, 0, 0, 0);
      st = __builtin_amdgcn_mfma_f32_32x32x16_bf16(kf1, qfrag[1], st, 0, 0, 0);
      st = __builtin_amdgcn_mfma_f32_32x32x16_bf16(kf2, qfrag[2], st, 0, 0, 0);
      st = __builtin_amdgcn_mfma_f32_32x32x16_bf16(kf3, qfrag[3], st, 0, 0, 0);
      __builtin_amdgcn_s_setprio(0);

      if (masked) {
#pragma unroll
        for (int rr = 0; rr < 16; ++rr) {
          const int kg = k0 + (rr & 3) + 8 * (rr >> 2) + 4 * hi;
          if (kg > q_glob) st[rr] = -1e30f;
        }
      }
      float m01 = fmaxf(fmaxf(st[0], st[1]), st[2]);
      float m02 = fmaxf(fmaxf(st[3], st[4]), st[5]);
      float m03 = fmaxf(fmaxf(st[6], st[7]), st[8]);
      float m04 = fmaxf(fmaxf(st[9], st[10]), st[11]);
      float m05 = fmaxf(fmaxf(st[12], st[13]), st[14]);
      float m06 = fmaxf(fmaxf(m01, m02), m03);
      float m07 = fmaxf(fmaxf(m04, m05), st[15]);
      const float bmax = fmaxf(m06, m07);
      if (__any(bmax > m_run + 8.f)) {        // T13 defer-max
        const float rmax = fmaxf(bmax, __shfl_xor(bmax, 32));
        const float mnew = fmaxf(m_run, rmax);
        const float corr = fexp2(m_run - mnew);
#pragma unroll
        for (int i = 0; i < 16; ++i) { acc0[i] *= corr; acc1[i] *= corr; }
        accL[0] *= corr;
        m_run = mnew;
      }
      float pp[16];
#pragma unroll
      for (int rr = 0; rr < 16; ++rr) pp[rr] = fexp2(st[rr] - m_run);

      unsigned wp[8];
#pragma unroll
      for (int i = 0; i < 8; ++i) wp[i] = cvtpk(pp[2 * i], pp[2 * i + 1]);
      plswap(wp[0], wp[2]); plswap(wp[1], wp[3]);
      plswap(wp[4], wp[6]); plswap(wp[5], wp[7]);
      union fu { unsigned uu2[4]; bf16x8 v; };
      fu f1, f2;
      f1.uu2[0] = wp[0]; f1.uu2[1] = wp[1]; f1.uu2[2] = wp[2]; f1.uu2[3] = wp[3];
      f2.uu2[0] = wp[4]; f2.uu2[1] = wp[5]; f2.uu2[2] = wp[6]; f2.uu2[3] = wp[7];

      bf16x8 vf0 = *(const bf16x8*)&lds[base + v0idx];
      bf16x8 vf1 = *(const bf16x8*)&lds[base + v1idx];
      bf16x8 vf2 = *(const bf16x8*)&lds[base + v2idx];
      bf16x8 vf3 = *(const bf16x8*)&lds[base + v3idx];

      __builtin_amdgcn_s_setprio(1);
      acc0 = __builtin_amdgcn_mfma_f32_32x32x16_bf16(vf0, f1.v, acc0, 0, 0, 0);
      acc0 = __builtin_amdgcn_mfma_f32_32x32x16_bf16(vf1, f2.v, acc0, 0, 0, 0);
      acc1 = __builtin_amdgcn_mfma_f32_32x32x16_bf16(vf2, f1.v, acc1, 0, 0, 0);
      acc1 = __builtin_amdgcn_mfma_f32_32x32x16_bf16(vf3, f2.v, acc1, 0, 0, 0);
      accL = __builtin_amdgcn_mfma_f32_32x32x16_bf16(onesf.v, f1.v, accL, 0, 0, 0);
      accL = __builtin_amdgcn_mfma_f32_32x32x16_bf16(onesf.v, f2.v, accL, 0, 0, 0);
      __builtin_amdgcn_s_setprio(0);
    }

    if (more) {
      const int nb = (buf ^ 1) * 1024;
      lds[nb + wKidx] = kA;
      lds[nb + wVidx] = vA;
    }
    __syncthreads();
    buf ^= 1;
  }

  // ---- split-k merge: h=1 publishes partials, h=0 merges & stores ----
  float cA = 1.f, cB = 0.f, l_mrg = 0.f;
  if (h == 1) {
    const int fb = spair * 1216 + lane * 19;
#pragma unroll
    for (int i = 0; i < 16; ++i) lf[fb + i] = acc0[i];
    lf[fb + 16] = m_run;
    lf[fb + 17] = accL[0];
  }
  __syncthreads();
  if (h == 0) {
    const int fb = spair * 1216 + lane * 19;
    const float mB = lf[fb + 16], lB = lf[fb + 17];
    const float mM = fmaxf(m_run, mB);
    cA = fexp2(m_run - mM);
    cB = fexp2(mB - mM);
    l_mrg = accL[0] * cA + lB * cB;
#pragma unroll
    for (int i = 0; i < 16; ++i) acc0[i] = acc0[i] * cA + lf[fb + i] * cB;
  }
  __syncthreads();
  if (h == 1) {
    const int fb2 = spair * 1088 + lane * 17;
#pragma unroll
    for (int i = 0; i < 16; ++i) lf[fb2 + i] = acc1[i];
  }
  __syncthreads();
  if (h == 0) {
    const int fb2 = spair * 1088 + lane * 17;
#pragma unroll
    for (int i = 0; i < 16; ++i) acc1[i] = acc1[i] * cA + lf[fb2 + i] * cB;
    const float inv = 1.f / l_mrg;
    bf16_t* yrow = y + (size_t)(b * T_SEQ + q_glob) * D_MODEL + hd * HD;
#pragma unroll
    for (int gg = 0; gg < 4; ++gg) {
      uint2 o0, o1;
      o0.x = cvtpk(acc0[4 * gg + 0] * inv, acc0[4 * gg + 1] * inv);
      o0.y = cvtpk(acc0[4 * gg + 2] * inv, acc0[4 * gg + 3] * inv);
      o1.x = cvtpk(acc1[4 * gg + 0] * inv, acc1[4 * gg + 1] * inv);
      o1.y = cvtpk(acc1[4 * gg + 2] * inv, acc1[4 * gg + 3] * inv);
      *(uint2*)(yrow + 8 * gg + 4 * hi)      = o0;
      *(uint2*)(yrow + 32 + 8 * gg + 4 * hi) = o1;
    }
  }
}

// ---------------------------------------------------------------------------
extern "C" void kernel_launch(void* const* d_in, const int* in_sizes, int n_in,
                              void* d_out, int out_size, void* d_ws,
                              size_t ws_size, hipStream_t stream) {
  const float* x    = (const float*)d_in[0];
  const float* cosb = (const float*)d_in[1];
  const float* sinb = (const float*)d_in[2];
  const float* Wq   = (const float*)d_in[3];
  const float* Wk   = (const float*)d_in[4];
  const float* Wv   = (const float*)d_in[5];
  const float* Wo   = (const float*)d_in[6];
  const float* qs   = (const float*)d_in[7];
  const float* ks   = (const float*)d_in[8];
  float* out = (float*)d_out;   // reference output dtype is float32

  char* ws = (char*)d_ws;
  bf16_t* qkv   = (bf16_t*)ws;                       // 25165824 B
  bf16_t* v_t   = (bf16_t*)(ws + 25165824);          // 4194304 B
  bf16_t* y     = (bf16_t*)(ws + 29360128);          // 16777216 B (= xb alias)
  bf16_t* xb    = y;                                 // xb dead before attn writes y
  bf16_t* wqkvb = (bf16_t*)(ws + 46137344);          // 3145728 B
  bf16_t* wob   = (bf16_t*)(ws + 49283072);          // 2097152 B

  // 0. fp32 -> bf16 converts (one launch: x + all weights)
  all_cvt<<<dim3(2688), 256, 0, stream>>>(x, Wq, Wk, Wv, Wo, xb, wqkvb, wob);

  // 1. fused QKV projection + RMSNorm + RoPE + V-transpose (XCD-clustered)
  gemm_bb<1, 12, bf16_t><<<dim3(768), 256, 0, stream>>>(
      xb, wqkvb, qkv, LDQKV, cosb, sinb, qs, ks, v_t);
  // 2. causal GQA flash attention -> y (unpaired quad blocks, grid 1024)
  attn<<<dim3(1024), 512, 0, stream>>>(qkv, v_t, y);
  // 3. output projection (XCD-clustered)
  gemm_bb<0, 8, float><<<dim3(512), 256, 0, stream>>>(
      y, wob, out, D_MODEL, nullptr, nullptr, nullptr, nullptr, nullptr);
}